// Round 1
// baseline (3034.007 us; speedup 1.0000x reference)
//
#include <hip/hip_runtime.h>
#include <math.h>

// ============================================================================
// FeatureAlign (PCD-style 2-level DCNv2 pyramid + SEM head), fp32 baseline.
//
// Structure:
//   up5 = up2x(feat_5);  cat5=[feat_4, 2*up5];  off5 = W_off5 @ cat5
//   om5 = conv3x3(off5) + b_om5
//   col5 = modulated-deform-samples(up5, om5)   [2304 x HW]
//   a5  = relu(W_dcn5 @ col5 + b_dcn5)
//   f4n = W_c1 @ [a5, feat_4]
//   up4 = up2x(f4n);  cat4=[feat_3, 2*up4];  off4 = W_off4 @ cat4
//   om4 = conv3x3(off4) + b_om4
//   col4 = samples(up4, om4);  f4a = relu(W_dcn4 @ col4 + b_dcn4)
//   f3c = [f4a, feat_3]   (512ch @64x64)
//   avg/max over ch of up2x(f3c) @128^2 -> conv7x7 -> BN -> sigmoid -> sa
//   z = W_sem @ f3c (64^2)  [conv1x1 commutes with bilinear up]
//   y = (1+sa) * up2x(z);  out = GroupNorm32(y) * g + b
// ============================================================================

static inline int cdiv(long long a, long long b) { return (int)((a + b - 1) / b); }

// ---------------- transpose weights: At[k][m] = A[m][k] ----------------
__global__ void transpose_kernel(const float* __restrict__ A, float* __restrict__ At,
                                 int M, int K) {
  long long idx = (long long)blockIdx.x * blockDim.x + threadIdx.x;
  if (idx >= (long long)M * K) return;
  int m = (int)(idx % M);
  long long k = idx / M;
  At[idx] = A[(long long)m * K + k];
}

// ---------------- bilinear 2x upsample (half-pixel, edge clamp) ----------------
__global__ void upsample2x_kernel(const float* __restrict__ in, float* __restrict__ out,
                                  int CB, int H, int W) {
  int OH = H * 2, OW = W * 2;
  long long total = (long long)CB * OH * OW;
  long long idx = (long long)blockIdx.x * blockDim.x + threadIdx.x;
  if (idx >= total) return;
  int ow = (int)(idx % OW);
  long long t = idx / OW;
  int oh = (int)(t % OH);
  int cb = (int)(t / OH);
  int iy = oh >> 1, ix = ow >> 1;
  int iy2 = (oh & 1) ? min(iy + 1, H - 1) : max(iy - 1, 0);
  int ix2 = (ow & 1) ? min(ix + 1, W - 1) : max(ix - 1, 0);
  const float* p = in + (long long)cb * H * W;
  out[idx] = 0.5625f * p[iy * W + ix] + 0.1875f * (p[iy * W + ix2] + p[iy2 * W + ix])
           + 0.0625f * p[iy2 * W + ix2];
}

// ---------------- channel concat: out[b] = [A[b], scale*B[b]] ----------------
__global__ void concat_kernel(const float* __restrict__ A, const float* __restrict__ Bp,
                              float* __restrict__ out, int C1, int C2, int HW, float scale) {
  long long idx = (long long)blockIdx.x * blockDim.x + threadIdx.x;
  long long total = 4LL * (C1 + C2) * HW;
  if (idx >= total) return;
  int p = (int)(idx % HW);
  long long t = idx / HW;
  int c = (int)(t % (C1 + C2));
  int b = (int)(t / (C1 + C2));
  float v;
  if (c < C1) v = A[((long long)b * C1 + c) * HW + p];
  else        v = scale * Bp[((long long)b * C2 + (c - C1)) * HW + p];
  out[idx] = v;
}

// ---------------- fp32 GEMM: C[z][M][N] = At^T @ B[z] (+bias)(relu) ----------------
// At: [K][M] (pre-transposed weights), B per z: [K][N]. Tile 128x128, BK=16, 8x8/thread.
template <int RELU>
__global__ __launch_bounds__(256) void gemm_kernel(
    const float* __restrict__ At, const float* __restrict__ B, float* __restrict__ C,
    const float* __restrict__ bias, int M, int N, int K, long long sB, long long sC) {
  __shared__ float As[16][128];
  __shared__ float Bs[16][128];
  int tid = threadIdx.x;
  int bm = blockIdx.y * 128, bn = blockIdx.x * 128;
  const float* Bb = B + (long long)blockIdx.z * sB;
  float* Cb = C + (long long)blockIdx.z * sC;
  float acc[8][8] = {};
  int tx = tid & 15, ty = tid >> 4;
  for (int k0 = 0; k0 < K; k0 += 16) {
#pragma unroll
    for (int r = 0; r < 8; r++) {
      int e = (r << 8) + tid;       // 0..2047
      int kk = e >> 7, m = e & 127; // consecutive tid -> m fast: coalesced, no LDS conflict
      As[kk][m] = At[(long long)(k0 + kk) * M + bm + m];
      Bs[kk][m] = Bb[(long long)(k0 + kk) * N + bn + m];
    }
    __syncthreads();
#pragma unroll
    for (int kk = 0; kk < 16; kk++) {
      float4 a0 = *(const float4*)&As[kk][ty * 8];
      float4 a1 = *(const float4*)&As[kk][ty * 8 + 4];
      float4 b0 = *(const float4*)&Bs[kk][tx * 8];
      float4 b1 = *(const float4*)&Bs[kk][tx * 8 + 4];
      float av[8] = {a0.x, a0.y, a0.z, a0.w, a1.x, a1.y, a1.z, a1.w};
      float bv[8] = {b0.x, b0.y, b0.z, b0.w, b1.x, b1.y, b1.z, b1.w};
#pragma unroll
      for (int i = 0; i < 8; i++)
#pragma unroll
        for (int j = 0; j < 8; j++) acc[i][j] += av[i] * bv[j];
    }
    __syncthreads();
  }
#pragma unroll
  for (int i = 0; i < 8; i++) {
    int m = bm + ty * 8 + i;
    float bv = bias ? bias[m] : 0.f;
#pragma unroll
    for (int j = 0; j < 8; j++) {
      float v = acc[i][j] + bv;
      if (RELU) v = fmaxf(v, 0.f);
      Cb[(long long)m * N + bn + tx * 8 + j] = v;
    }
  }
}

// ---------------- direct conv3x3, pad 1 (256 -> 216) ----------------
// block: 16x16 spatial tile, 8 output channels per block-chunk; LDS-staged input.
__global__ __launch_bounds__(256) void conv3x3_kernel(
    const float* __restrict__ in, const float* __restrict__ w, const float* __restrict__ bias,
    float* __restrict__ out, int H, int W, int Cin, int Cout) {
  int tilesX = W >> 4;
  int tx0 = (blockIdx.x % tilesX) << 4;
  int ty0 = (blockIdx.x / tilesX) << 4;
  int o0 = blockIdx.y << 3;
  const float* inb = in + (long long)blockIdx.z * Cin * H * W;
  __shared__ float s[8][18][18];
  int tid = threadIdx.x;
  int px = tid & 15, py = tid >> 4;
  float acc[8] = {};
  for (int c0 = 0; c0 < Cin; c0 += 8) {
    for (int e = tid; e < 8 * 324; e += 256) {
      int c = e / 324;
      int r = e - c * 324;
      int yy = r / 18, xx = r - yy * 18;
      int gy = ty0 + yy - 1, gx = tx0 + xx - 1;
      float v = 0.f;
      if (gy >= 0 && gy < H && gx >= 0 && gx < W)
        v = inb[(long long)(c0 + c) * H * W + gy * W + gx];
      s[c][yy][xx] = v;
    }
    __syncthreads();
#pragma unroll
    for (int c = 0; c < 8; c++) {
      float v[9];
#pragma unroll
      for (int dy = 0; dy < 3; dy++)
#pragma unroll
        for (int dx = 0; dx < 3; dx++) v[dy * 3 + dx] = s[c][py + dy][px + dx];
#pragma unroll
      for (int o = 0; o < 8; o++) {
        const float* wp = w + ((long long)(o0 + o) * Cin + (c0 + c)) * 9;
#pragma unroll
        for (int k = 0; k < 9; k++) acc[o] += wp[k] * v[k];
      }
    }
    __syncthreads();
  }
  float* outb = out + ((long long)blockIdx.z * Cout + o0) * H * W;
  int pofs = (ty0 + py) * W + tx0 + px;
#pragma unroll
  for (int o = 0; o < 8; o++) outb[(long long)o * H * W + pofs] = acc[o] + bias[o0 + o];
}

// ---------------- DCNv2 column build: col[bz][(g*32+c)*9+k][p] ----------------
__global__ void dcn_col_kernel(const float* __restrict__ x, const float* __restrict__ om,
                               float* __restrict__ col, int H, int W, int b0) {
  int HW = H * W;
  int p = blockIdx.x * 256 + threadIdx.x;
  int gk = blockIdx.y;           // 0..71
  int g = gk / 9, k9 = gk - g * 9;
  int bz = blockIdx.z;
  int b = b0 + bz;
  int h = p / W, wc = p - h * W;
  const float* omb = om + (long long)b * 216 * HW;
  float offy = omb[(long long)gk * HW + p];
  float offx = omb[(long long)(72 + gk) * HW + p];
  float mraw = omb[(long long)(144 + gk) * HW + p];
  float mask = 1.f / (1.f + expf(-mraw));
  float y = (float)h + (float)(k9 / 3 - 1) + offy;
  float xx = (float)wc + (float)(k9 % 3 - 1) + offx;
  float y0f = floorf(y), x0f = floorf(xx);
  int y0 = (int)y0f, x0 = (int)x0f;
  float fy = y - y0f, fx = xx - x0f;
  float w00 = (1.f - fy) * (1.f - fx), w01 = (1.f - fy) * fx;
  float w10 = fy * (1.f - fx), w11 = fy * fx;
  bool iy0 = (y0 >= 0) & (y0 < H), iy1 = (y0 + 1 >= 0) & (y0 + 1 < H);
  bool ix0 = (x0 >= 0) & (x0 < W), ix1 = (x0 + 1 >= 0) & (x0 + 1 < W);
  w00 = (iy0 & ix0) ? w00 : 0.f;
  w01 = (iy0 & ix1) ? w01 : 0.f;
  w10 = (iy1 & ix0) ? w10 : 0.f;
  w11 = (iy1 & ix1) ? w11 : 0.f;
  int y0c = min(max(y0, 0), H - 1), y1c = min(max(y0 + 1, 0), H - 1);
  int x0c = min(max(x0, 0), W - 1), x1c = min(max(x0 + 1, 0), W - 1);
  int i00 = y0c * W + x0c, i01 = y0c * W + x1c, i10 = y1c * W + x0c, i11 = y1c * W + x1c;
  const float* xb = x + ((long long)b * 256 + g * 32) * HW;
  float* cb = col + ((long long)bz * 2304 + (long long)(g * 32) * 9 + k9) * HW + p;
#pragma unroll 4
  for (int c = 0; c < 32; c++) {
    const float* xc = xb + (long long)c * HW;
    float v = w00 * xc[i00] + w01 * xc[i01] + w10 * xc[i10] + w11 * xc[i11];
    cb[(long long)c * 9 * HW] = v * mask;
  }
}

// ---------------- channel avg/max of up2x(f3c) at 128x128 ----------------
__global__ void avgmax_kernel(const float* __restrict__ f3c, float* __restrict__ am) {
  int idx = blockIdx.x * 256 + threadIdx.x; // 4*16384
  int b = idx >> 14, p = idx & 16383;
  int oh = p >> 7, ow = p & 127;
  int iy = oh >> 1, ix = ow >> 1;
  int iy2 = (oh & 1) ? min(iy + 1, 63) : max(iy - 1, 0);
  int ix2 = (ow & 1) ? min(ix + 1, 63) : max(ix - 1, 0);
  int i00 = iy * 64 + ix, i01 = iy * 64 + ix2, i10 = iy2 * 64 + ix, i11 = iy2 * 64 + ix2;
  const float* base = f3c + (long long)b * 512 * 4096;
  float sum = 0.f, mx = -3.4e38f;
  for (int c = 0; c < 512; c++) {
    const float* pc = base + (long long)c * 4096;
    float v = 0.5625f * pc[i00] + 0.1875f * (pc[i01] + pc[i10]) + 0.0625f * pc[i11];
    sum += v;
    mx = fmaxf(mx, v);
  }
  am[(long long)b * 2 * 16384 + p] = sum * (1.f / 512.f);
  am[(long long)b * 2 * 16384 + 16384 + p] = mx;
}

// ---------------- conv7x7 (2->1) + BN + sigmoid -> sa ----------------
__global__ void sa_kernel(const float* __restrict__ am, const float* __restrict__ w_sa,
                          const float* __restrict__ bn_g, const float* __restrict__ bn_b,
                          const float* __restrict__ bn_m, const float* __restrict__ bn_v,
                          float* __restrict__ sa) {
  int idx = blockIdx.x * 256 + threadIdx.x; // 4*16384
  int b = idx >> 14, p = idx & 16383;
  int oh = p >> 7, ow = p & 127;
  float acc = 0.f;
  for (int ci = 0; ci < 2; ci++) {
    const float* base = am + ((long long)b * 2 + ci) * 16384;
    for (int dy = 0; dy < 7; dy++) {
      int yy = oh + dy - 3;
      if (yy < 0 || yy > 127) continue;
      for (int dx = 0; dx < 7; dx++) {
        int xx = ow + dx - 3;
        if (xx < 0 || xx > 127) continue;
        acc += w_sa[ci * 49 + dy * 7 + dx] * base[yy * 128 + xx];
      }
    }
  }
  float a = (acc - bn_m[0]) * rsqrtf(bn_v[0] + 1e-5f);
  a = a * bn_g[0] + bn_b[0];
  sa[idx] = 1.f / (1.f + expf(-a));
}

// ---------------- y = (1+sa) * up2x(z) ----------------
__global__ void final_y_kernel(const float* __restrict__ z, const float* __restrict__ sa,
                               float* __restrict__ out) {
  long long idx = (long long)blockIdx.x * 256 + threadIdx.x; // 16,777,216
  int ow = (int)(idx & 127);
  long long t = idx >> 7;
  int oh = (int)(t & 127);
  t >>= 7;
  int c = (int)(t & 255);
  int b = (int)(t >> 8);
  int iy = oh >> 1, ix = ow >> 1;
  int iy2 = (oh & 1) ? min(iy + 1, 63) : max(iy - 1, 0);
  int ix2 = (ow & 1) ? min(ix + 1, 63) : max(ix - 1, 0);
  const float* zp = z + (long long)(b * 256 + c) * 4096;
  float v = 0.5625f * zp[iy * 64 + ix] + 0.1875f * (zp[iy * 64 + ix2] + zp[iy2 * 64 + ix])
          + 0.0625f * zp[iy2 * 64 + ix2];
  float s = sa[((long long)b << 14) + (oh << 7) + ow];
  out[idx] = v * (1.f + s);
}

// ---------------- GroupNorm (32 groups over 256ch) ----------------
__global__ __launch_bounds__(256) void gn_stats_kernel(const float* __restrict__ y,
                                                       float* __restrict__ stats) {
  int bg = blockIdx.x; // 0..127
  int b = bg >> 5, g = bg & 31;
  const float* base = y + ((long long)b * 256 + g * 8) * 16384;
  float s = 0.f, ss = 0.f;
  for (int i = threadIdx.x; i < 8 * 16384; i += 256) {
    float v = base[i];
    s += v;
    ss += v * v;
  }
#pragma unroll
  for (int off = 32; off > 0; off >>= 1) {
    s += __shfl_down(s, off);
    ss += __shfl_down(ss, off);
  }
  __shared__ float rs[2][4];
  int lane = threadIdx.x & 63, wv = threadIdx.x >> 6;
  if (lane == 0) { rs[0][wv] = s; rs[1][wv] = ss; }
  __syncthreads();
  if (threadIdx.x == 0) {
    float S = rs[0][0] + rs[0][1] + rs[0][2] + rs[0][3];
    float SS = rs[1][0] + rs[1][1] + rs[1][2] + rs[1][3];
    float n = 8.f * 16384.f;
    float mu = S / n;
    float var = SS / n - mu * mu;
    stats[bg * 2] = mu;
    stats[bg * 2 + 1] = rsqrtf(var + 1e-5f);
  }
}

__global__ void gn_apply_kernel(float* __restrict__ y, const float* __restrict__ stats,
                                const float* __restrict__ gg, const float* __restrict__ gb) {
  long long idx = (long long)blockIdx.x * 256 + threadIdx.x;
  int c = (int)((idx >> 14) & 255);
  int b = (int)(idx >> 22);
  int bg = b * 32 + (c >> 3);
  float mu = stats[bg * 2], rstd = stats[bg * 2 + 1];
  y[idx] = (y[idx] - mu) * rstd * gg[c] + gb[c];
}

// ============================================================================

extern "C" void kernel_launch(void* const* d_in, const int* in_sizes, int n_in,
                              void* d_out, int out_size, void* d_ws, size_t ws_size,
                              hipStream_t stream) {
  const float* feat_3 = (const float*)d_in[1];
  const float* feat_4 = (const float*)d_in[2];
  const float* feat_5 = (const float*)d_in[3];
  const float* w_off5 = (const float*)d_in[4];
  const float* w_om5  = (const float*)d_in[5];
  const float* b_om5  = (const float*)d_in[6];
  const float* w_dcn5 = (const float*)d_in[7];
  const float* b_dcn5 = (const float*)d_in[8];
  const float* w_c1   = (const float*)d_in[9];
  const float* w_off4 = (const float*)d_in[10];
  const float* w_om4  = (const float*)d_in[11];
  const float* b_om4  = (const float*)d_in[12];
  const float* w_dcn4 = (const float*)d_in[13];
  const float* b_dcn4 = (const float*)d_in[14];
  const float* w_sa   = (const float*)d_in[15];
  const float* bn_g   = (const float*)d_in[16];
  const float* bn_b   = (const float*)d_in[17];
  const float* bn_m   = (const float*)d_in[18];
  const float* bn_v   = (const float*)d_in[19];
  const float* w_sem  = (const float*)d_in[20];
  const float* gn_g   = (const float*)d_in[21];
  const float* gn_b   = (const float*)d_in[22];
  float* out = (float*)d_out;
  float* ws = (float*)d_ws;

  // ---- workspace layout (floats); aliases noted ----
  const long long o_T    = 0;                        // 1,703,936 transposed weights
  const long long o_up5  = o_T + 1703936;            // 1,048,576 (alias later: am/sa/gnstats)
  const long long o_off5 = o_up5 + 1048576;          // 1,048,576
  const long long o_om5  = o_off5 + 1048576;         // 884,736
  const long long o_a5   = o_om5 + 884736;           // 1,048,576
  const long long o_f4n  = o_a5 + 1048576;           // 1,048,576
  const long long o_up4  = o_f4n + 1048576;          // 4,194,304 (alias later: z64)
  const long long o_off4 = o_up4 + 4194304;          // 4,194,304 (alias later: f4a)
  const long long o_om4  = o_off4 + 4194304;         // 3,538,944
  const long long o_sh   = o_om4 + 3538944;          // shared: cat / col / f3c

  const long long colAll = 4LL * 2304 * 4096;        // 37,748,736
  const long long colPB  = 2304LL * 4096;            //  9,437,184
  bool allb = ws_size >= (size_t)(o_sh + colAll) * 4;

  float* wT_off5 = ws + o_T;
  float* wT_dcn5 = wT_off5 + 131072;
  float* wT_c1   = wT_dcn5 + 589824;
  float* wT_off4 = wT_c1 + 131072;
  float* wT_dcn4 = wT_off4 + 131072;
  float* wT_sem  = wT_dcn4 + 589824;
  float* up5  = ws + o_up5;
  float* off5 = ws + o_off5;
  float* om5  = ws + o_om5;
  float* a5   = ws + o_a5;
  float* f4n  = ws + o_f4n;
  float* up4  = ws + o_up4;
  float* off4 = ws + o_off4;
  float* om4  = ws + o_om4;
  float* shared = ws + o_sh;
  float* f4a  = off4;               // alias (off4 dead after conv3x3 om4)
  float* z64  = up4;                // alias (up4 dead after col4 build)
  float* am   = up5;                // alias (up5 dead after col5 build)
  float* sa   = am + 131072;
  float* gnst = sa + 65536;

  dim3 blk(256);

  // ---- transpose all GEMM weights ----
  transpose_kernel<<<cdiv(256LL * 512, 256), blk, 0, stream>>>(w_off5, wT_off5, 256, 512);
  transpose_kernel<<<cdiv(256LL * 2304, 256), blk, 0, stream>>>(w_dcn5, wT_dcn5, 256, 2304);
  transpose_kernel<<<cdiv(256LL * 512, 256), blk, 0, stream>>>(w_c1, wT_c1, 256, 512);
  transpose_kernel<<<cdiv(256LL * 512, 256), blk, 0, stream>>>(w_off4, wT_off4, 256, 512);
  transpose_kernel<<<cdiv(256LL * 2304, 256), blk, 0, stream>>>(w_dcn4, wT_dcn4, 256, 2304);
  transpose_kernel<<<cdiv(256LL * 512, 256), blk, 0, stream>>>(w_sem, wT_sem, 256, 512);

  // ---- stage A (32x32) ----
  upsample2x_kernel<<<cdiv(1024LL * 32 * 32, 256), blk, 0, stream>>>(feat_5, up5, 1024, 16, 16);
  concat_kernel<<<cdiv(4LL * 512 * 1024, 256), blk, 0, stream>>>(feat_4, up5, shared, 256, 256, 1024, 2.f);
  gemm_kernel<0><<<dim3(8, 2, 4), blk, 0, stream>>>(wT_off5, shared, off5, nullptr,
                                                    256, 1024, 512, 512LL * 1024, 256LL * 1024);
  conv3x3_kernel<<<dim3(4, 27, 4), blk, 0, stream>>>(off5, w_om5, b_om5, om5, 32, 32, 256, 216);
  dcn_col_kernel<<<dim3(4, 72, 4), blk, 0, stream>>>(up5, om5, shared, 32, 32, 0);
  gemm_kernel<1><<<dim3(8, 2, 4), blk, 0, stream>>>(wT_dcn5, shared, a5, b_dcn5,
                                                    256, 1024, 2304, 2304LL * 1024, 256LL * 1024);
  concat_kernel<<<cdiv(4LL * 512 * 1024, 256), blk, 0, stream>>>(a5, feat_4, shared, 256, 256, 1024, 1.f);
  gemm_kernel<0><<<dim3(8, 2, 4), blk, 0, stream>>>(wT_c1, shared, f4n, nullptr,
                                                    256, 1024, 512, 512LL * 1024, 256LL * 1024);

  // ---- stage B (64x64) ----
  upsample2x_kernel<<<cdiv(1024LL * 64 * 64, 256), blk, 0, stream>>>(f4n, up4, 1024, 32, 32);
  concat_kernel<<<cdiv(4LL * 512 * 4096, 256), blk, 0, stream>>>(feat_3, up4, shared, 256, 256, 4096, 2.f);
  gemm_kernel<0><<<dim3(32, 2, 4), blk, 0, stream>>>(wT_off4, shared, off4, nullptr,
                                                     256, 4096, 512, 512LL * 4096, 256LL * 4096);
  conv3x3_kernel<<<dim3(16, 27, 4), blk, 0, stream>>>(off4, w_om4, b_om4, om4, 64, 64, 256, 216);
  if (allb) {
    dcn_col_kernel<<<dim3(16, 72, 4), blk, 0, stream>>>(up4, om4, shared, 64, 64, 0);
    gemm_kernel<1><<<dim3(32, 2, 4), blk, 0, stream>>>(wT_dcn4, shared, f4a, b_dcn4,
                                                       256, 4096, 2304, colPB, 256LL * 4096);
  } else {
    for (int b = 0; b < 4; b++) {
      dcn_col_kernel<<<dim3(16, 72, 1), blk, 0, stream>>>(up4, om4, shared, 64, 64, b);
      gemm_kernel<1><<<dim3(32, 2, 1), blk, 0, stream>>>(wT_dcn4, shared, f4a + (long long)b * 256 * 4096,
                                                         b_dcn4, 256, 4096, 2304, 0, 0);
    }
  }
  concat_kernel<<<cdiv(4LL * 512 * 4096, 256), blk, 0, stream>>>(f4a, feat_3, shared, 256, 256, 4096, 1.f);

  // ---- SEM head ----
  avgmax_kernel<<<256, blk, 0, stream>>>(shared, am);
  sa_kernel<<<256, blk, 0, stream>>>(am, w_sa, bn_g, bn_b, bn_m, bn_v, sa);
  gemm_kernel<0><<<dim3(32, 2, 4), blk, 0, stream>>>(wT_sem, shared, z64, nullptr,
                                                     256, 4096, 512, 512LL * 4096, 256LL * 4096);
  final_y_kernel<<<65536, blk, 0, stream>>>(z64, sa, out);
  gn_stats_kernel<<<128, blk, 0, stream>>>(out, gnst);
  gn_apply_kernel<<<65536, blk, 0, stream>>>(out, gnst, gn_g, gn_b);
}

// Round 2
// 2578.412 us; speedup vs baseline: 1.1767x; 1.1767x over previous
//
#include <hip/hip_runtime.h>
#include <math.h>

// ============================================================================
// FeatureAlign (PCD-style 2-level DCNv2 pyramid + SEM head), fp32.
// R1: conv3x3 offset-mask convs -> implicit GEMM (was VMEM-issue-bound with
//     per-FMA global weight loads, 64.8 GB FETCH_SIZE, ~1250 us combined).
// ============================================================================

static inline int cdiv(long long a, long long b) { return (int)((a + b - 1) / b); }

// ---------------- transpose weights: At[k][m] = A[m][k] ----------------
__global__ void transpose_kernel(const float* __restrict__ A, float* __restrict__ At,
                                 int M, int K) {
  long long idx = (long long)blockIdx.x * blockDim.x + threadIdx.x;
  if (idx >= (long long)M * K) return;
  int m = (int)(idx % M);
  long long k = idx / M;
  At[idx] = A[(long long)m * K + k];
}

// ---------------- transpose + pad rows to Mp: At[k][m] ----------------
__global__ void transpose_pad_kernel(const float* __restrict__ A, float* __restrict__ At,
                                     int M, int K, int Mp) {
  long long idx = (long long)blockIdx.x * blockDim.x + threadIdx.x;
  if (idx >= (long long)Mp * K) return;
  int m = (int)(idx % Mp);
  long long k = idx / Mp;
  At[idx] = (m < M) ? A[(long long)m * K + k] : 0.f;
}

// ---------------- bilinear 2x upsample (half-pixel, edge clamp) ----------------
__global__ void upsample2x_kernel(const float* __restrict__ in, float* __restrict__ out,
                                  int CB, int H, int W) {
  int OH = H * 2, OW = W * 2;
  long long total = (long long)CB * OH * OW;
  long long idx = (long long)blockIdx.x * blockDim.x + threadIdx.x;
  if (idx >= total) return;
  int ow = (int)(idx % OW);
  long long t = idx / OW;
  int oh = (int)(t % OH);
  int cb = (int)(t / OH);
  int iy = oh >> 1, ix = ow >> 1;
  int iy2 = (oh & 1) ? min(iy + 1, H - 1) : max(iy - 1, 0);
  int ix2 = (ow & 1) ? min(ix + 1, W - 1) : max(ix - 1, 0);
  const float* p = in + (long long)cb * H * W;
  out[idx] = 0.5625f * p[iy * W + ix] + 0.1875f * (p[iy * W + ix2] + p[iy2 * W + ix])
           + 0.0625f * p[iy2 * W + ix2];
}

// ---------------- channel concat: out[b] = [A[b], scale*B[b]] ----------------
__global__ void concat_kernel(const float* __restrict__ A, const float* __restrict__ Bp,
                              float* __restrict__ out, int C1, int C2, int HW, float scale) {
  long long idx = (long long)blockIdx.x * blockDim.x + threadIdx.x;
  long long total = 4LL * (C1 + C2) * HW;
  if (idx >= total) return;
  int p = (int)(idx % HW);
  long long t = idx / HW;
  int c = (int)(t % (C1 + C2));
  int b = (int)(t / (C1 + C2));
  float v;
  if (c < C1) v = A[((long long)b * C1 + c) * HW + p];
  else        v = scale * Bp[((long long)b * C2 + (c - C1)) * HW + p];
  out[idx] = v;
}

// ---------------- fp32 GEMM: C[z][M][N] = At^T @ B[z] (+bias)(relu) ----------------
// At: [K][M] (pre-transposed weights), B per z: [K][N]. Tile 128x128, BK=16, 8x8/thread.
template <int RELU>
__global__ __launch_bounds__(256) void gemm_kernel(
    const float* __restrict__ At, const float* __restrict__ B, float* __restrict__ C,
    const float* __restrict__ bias, int M, int N, int K, long long sB, long long sC) {
  __shared__ float As[16][128];
  __shared__ float Bs[16][128];
  int tid = threadIdx.x;
  int bm = blockIdx.y * 128, bn = blockIdx.x * 128;
  const float* Bb = B + (long long)blockIdx.z * sB;
  float* Cb = C + (long long)blockIdx.z * sC;
  float acc[8][8] = {};
  int tx = tid & 15, ty = tid >> 4;
  for (int k0 = 0; k0 < K; k0 += 16) {
#pragma unroll
    for (int r = 0; r < 8; r++) {
      int e = (r << 8) + tid;       // 0..2047
      int kk = e >> 7, m = e & 127; // consecutive tid -> m fast: coalesced, no LDS conflict
      As[kk][m] = At[(long long)(k0 + kk) * M + bm + m];
      Bs[kk][m] = Bb[(long long)(k0 + kk) * N + bn + m];
    }
    __syncthreads();
#pragma unroll
    for (int kk = 0; kk < 16; kk++) {
      float4 a0 = *(const float4*)&As[kk][ty * 8];
      float4 a1 = *(const float4*)&As[kk][ty * 8 + 4];
      float4 b0 = *(const float4*)&Bs[kk][tx * 8];
      float4 b1 = *(const float4*)&Bs[kk][tx * 8 + 4];
      float av[8] = {a0.x, a0.y, a0.z, a0.w, a1.x, a1.y, a1.z, a1.w};
      float bv[8] = {b0.x, b0.y, b0.z, b0.w, b1.x, b1.y, b1.z, b1.w};
#pragma unroll
      for (int i = 0; i < 8; i++)
#pragma unroll
        for (int j = 0; j < 8; j++) acc[i][j] += av[i] * bv[j];
    }
    __syncthreads();
  }
#pragma unroll
  for (int i = 0; i < 8; i++) {
    int m = bm + ty * 8 + i;
    float bv = bias ? bias[m] : 0.f;
#pragma unroll
    for (int j = 0; j < 8; j++) {
      float v = acc[i][j] + bv;
      if (RELU) v = fmaxf(v, 0.f);
      Cb[(long long)m * N + bn + tx * 8 + j] = v;
    }
  }
}

// ---------------- conv3x3 as implicit GEMM ----------------
// At: [2304][256] (transposed, M-padded 216->256). X: [B][256][H][W].
// C: [B][216][HW]. k = c*9 + (dy+1)*3 + (dx+1). B-tile built from shifted rows.
template <int LOGW>
__global__ __launch_bounds__(256) void convgemm_kernel(
    const float* __restrict__ At, const float* __restrict__ X, float* __restrict__ C,
    const float* __restrict__ bias, int HW) {
  const int W = 1 << LOGW, H = HW >> LOGW;
  __shared__ float As[16][128];
  __shared__ float Bs[16][128];
  int tid = threadIdx.x;
  int bm = blockIdx.y * 128;         // 0 or 128 (rows >=216 are pad)
  int p0 = blockIdx.x * 128;
  const float* Xb = X + (long long)blockIdx.z * 256 * HW;
  float* Cb = C + (long long)blockIdx.z * 216 * HW;
  float acc[8][8] = {};
  int tx = tid & 15, ty = tid >> 4;
  for (int k0 = 0; k0 < 2304; k0 += 16) {
#pragma unroll
    for (int r = 0; r < 8; r++) {
      int e = (r << 8) + tid;
      int kk = e >> 7, m = e & 127;
      As[kk][m] = At[(long long)(k0 + kk) * 256 + bm + m];
    }
#pragma unroll
    for (int r = 0; r < 8; r++) {
      int e = (r << 8) + tid;
      int kk = e >> 7, j = e & 127;
      int k = k0 + kk;
      int c = k / 9;
      int t = k - c * 9;
      int dy = t / 3 - 1, dx = t - (t / 3) * 3 - 1;
      int p = p0 + j;
      int y = p >> LOGW, x = p & (W - 1);
      int sy = y + dy, sx = x + dx;
      float v = 0.f;
      if (sy >= 0 && sy < H && sx >= 0 && sx < W)
        v = Xb[((long long)c << (2 * LOGW)) + (sy << LOGW) + sx];
      Bs[kk][j] = v;
    }
    __syncthreads();
#pragma unroll
    for (int kk = 0; kk < 16; kk++) {
      float4 a0 = *(const float4*)&As[kk][ty * 8];
      float4 a1 = *(const float4*)&As[kk][ty * 8 + 4];
      float4 b0 = *(const float4*)&Bs[kk][tx * 8];
      float4 b1 = *(const float4*)&Bs[kk][tx * 8 + 4];
      float av[8] = {a0.x, a0.y, a0.z, a0.w, a1.x, a1.y, a1.z, a1.w};
      float bv[8] = {b0.x, b0.y, b0.z, b0.w, b1.x, b1.y, b1.z, b1.w};
#pragma unroll
      for (int i = 0; i < 8; i++)
#pragma unroll
        for (int j = 0; j < 8; j++) acc[i][j] += av[i] * bv[j];
    }
    __syncthreads();
  }
#pragma unroll
  for (int i = 0; i < 8; i++) {
    int m = bm + ty * 8 + i;
    if (m < 216) {
      float bv = bias[m];
#pragma unroll
      for (int j = 0; j < 8; j++)
        Cb[(long long)m * HW + p0 + tx * 8 + j] = acc[i][j] + bv;
    }
  }
}

// ---------------- DCNv2 column build: col[bz][(g*32+c)*9+k][p] ----------------
__global__ void dcn_col_kernel(const float* __restrict__ x, const float* __restrict__ om,
                               float* __restrict__ col, int H, int W, int b0) {
  int HW = H * W;
  int p = blockIdx.x * 256 + threadIdx.x;
  int gk = blockIdx.y;           // 0..71
  int g = gk / 9, k9 = gk - g * 9;
  int bz = blockIdx.z;
  int b = b0 + bz;
  int h = p / W, wc = p - h * W;
  const float* omb = om + (long long)b * 216 * HW;
  float offy = omb[(long long)gk * HW + p];
  float offx = omb[(long long)(72 + gk) * HW + p];
  float mraw = omb[(long long)(144 + gk) * HW + p];
  float mask = 1.f / (1.f + expf(-mraw));
  float y = (float)h + (float)(k9 / 3 - 1) + offy;
  float xx = (float)wc + (float)(k9 % 3 - 1) + offx;
  float y0f = floorf(y), x0f = floorf(xx);
  int y0 = (int)y0f, x0 = (int)x0f;
  float fy = y - y0f, fx = xx - x0f;
  float w00 = (1.f - fy) * (1.f - fx), w01 = (1.f - fy) * fx;
  float w10 = fy * (1.f - fx), w11 = fy * fx;
  bool iy0 = (y0 >= 0) & (y0 < H), iy1 = (y0 + 1 >= 0) & (y0 + 1 < H);
  bool ix0 = (x0 >= 0) & (x0 < W), ix1 = (x0 + 1 >= 0) & (x0 + 1 < W);
  w00 = (iy0 & ix0) ? w00 : 0.f;
  w01 = (iy0 & ix1) ? w01 : 0.f;
  w10 = (iy1 & ix0) ? w10 : 0.f;
  w11 = (iy1 & ix1) ? w11 : 0.f;
  int y0c = min(max(y0, 0), H - 1), y1c = min(max(y0 + 1, 0), H - 1);
  int x0c = min(max(x0, 0), W - 1), x1c = min(max(x0 + 1, 0), W - 1);
  int i00 = y0c * W + x0c, i01 = y0c * W + x1c, i10 = y1c * W + x0c, i11 = y1c * W + x1c;
  const float* xb = x + ((long long)b * 256 + g * 32) * HW;
  float* cb = col + ((long long)bz * 2304 + (long long)(g * 32) * 9 + k9) * HW + p;
#pragma unroll 4
  for (int c = 0; c < 32; c++) {
    const float* xc = xb + (long long)c * HW;
    float v = w00 * xc[i00] + w01 * xc[i01] + w10 * xc[i10] + w11 * xc[i11];
    cb[(long long)c * 9 * HW] = v * mask;
  }
}

// ---------------- channel avg/max of up2x(f3c) at 128x128 ----------------
__global__ void avgmax_kernel(const float* __restrict__ f3c, float* __restrict__ am) {
  int idx = blockIdx.x * 256 + threadIdx.x; // 4*16384
  int b = idx >> 14, p = idx & 16383;
  int oh = p >> 7, ow = p & 127;
  int iy = oh >> 1, ix = ow >> 1;
  int iy2 = (oh & 1) ? min(iy + 1, 63) : max(iy - 1, 0);
  int ix2 = (ow & 1) ? min(ix + 1, 63) : max(ix - 1, 0);
  int i00 = iy * 64 + ix, i01 = iy * 64 + ix2, i10 = iy2 * 64 + ix, i11 = iy2 * 64 + ix2;
  const float* base = f3c + (long long)b * 512 * 4096;
  float sum = 0.f, mx = -3.4e38f;
  for (int c = 0; c < 512; c++) {
    const float* pc = base + (long long)c * 4096;
    float v = 0.5625f * pc[i00] + 0.1875f * (pc[i01] + pc[i10]) + 0.0625f * pc[i11];
    sum += v;
    mx = fmaxf(mx, v);
  }
  am[(long long)b * 2 * 16384 + p] = sum * (1.f / 512.f);
  am[(long long)b * 2 * 16384 + 16384 + p] = mx;
}

// ---------------- conv7x7 (2->1) + BN + sigmoid -> sa ----------------
__global__ void sa_kernel(const float* __restrict__ am, const float* __restrict__ w_sa,
                          const float* __restrict__ bn_g, const float* __restrict__ bn_b,
                          const float* __restrict__ bn_m, const float* __restrict__ bn_v,
                          float* __restrict__ sa) {
  int idx = blockIdx.x * 256 + threadIdx.x; // 4*16384
  int b = idx >> 14, p = idx & 16383;
  int oh = p >> 7, ow = p & 127;
  float acc = 0.f;
  for (int ci = 0; ci < 2; ci++) {
    const float* base = am + ((long long)b * 2 + ci) * 16384;
    for (int dy = 0; dy < 7; dy++) {
      int yy = oh + dy - 3;
      if (yy < 0 || yy > 127) continue;
      for (int dx = 0; dx < 7; dx++) {
        int xx = ow + dx - 3;
        if (xx < 0 || xx > 127) continue;
        acc += w_sa[ci * 49 + dy * 7 + dx] * base[yy * 128 + xx];
      }
    }
  }
  float a = (acc - bn_m[0]) * rsqrtf(bn_v[0] + 1e-5f);
  a = a * bn_g[0] + bn_b[0];
  sa[idx] = 1.f / (1.f + expf(-a));
}

// ---------------- y = (1+sa) * up2x(z) ----------------
__global__ void final_y_kernel(const float* __restrict__ z, const float* __restrict__ sa,
                               float* __restrict__ out) {
  long long idx = (long long)blockIdx.x * 256 + threadIdx.x; // 16,777,216
  int ow = (int)(idx & 127);
  long long t = idx >> 7;
  int oh = (int)(t & 127);
  t >>= 7;
  int c = (int)(t & 255);
  int b = (int)(t >> 8);
  int iy = oh >> 1, ix = ow >> 1;
  int iy2 = (oh & 1) ? min(iy + 1, 63) : max(iy - 1, 0);
  int ix2 = (ow & 1) ? min(ix + 1, 63) : max(ix - 1, 0);
  const float* zp = z + (long long)(b * 256 + c) * 4096;
  float v = 0.5625f * zp[iy * 64 + ix] + 0.1875f * (zp[iy * 64 + ix2] + zp[iy2 * 64 + ix])
          + 0.0625f * zp[iy2 * 64 + ix2];
  float s = sa[((long long)b << 14) + (oh << 7) + ow];
  out[idx] = v * (1.f + s);
}

// ---------------- GroupNorm (32 groups over 256ch) ----------------
__global__ __launch_bounds__(256) void gn_stats_kernel(const float* __restrict__ y,
                                                       float* __restrict__ stats) {
  int bg = blockIdx.x; // 0..127
  int b = bg >> 5, g = bg & 31;
  const float* base = y + ((long long)b * 256 + g * 8) * 16384;
  float s = 0.f, ss = 0.f;
  for (int i = threadIdx.x; i < 8 * 16384; i += 256) {
    float v = base[i];
    s += v;
    ss += v * v;
  }
#pragma unroll
  for (int off = 32; off > 0; off >>= 1) {
    s += __shfl_down(s, off);
    ss += __shfl_down(ss, off);
  }
  __shared__ float rs[2][4];
  int lane = threadIdx.x & 63, wv = threadIdx.x >> 6;
  if (lane == 0) { rs[0][wv] = s; rs[1][wv] = ss; }
  __syncthreads();
  if (threadIdx.x == 0) {
    float S = rs[0][0] + rs[0][1] + rs[0][2] + rs[0][3];
    float SS = rs[1][0] + rs[1][1] + rs[1][2] + rs[1][3];
    float n = 8.f * 16384.f;
    float mu = S / n;
    float var = SS / n - mu * mu;
    stats[bg * 2] = mu;
    stats[bg * 2 + 1] = rsqrtf(var + 1e-5f);
  }
}

__global__ void gn_apply_kernel(float* __restrict__ y, const float* __restrict__ stats,
                                const float* __restrict__ gg, const float* __restrict__ gb) {
  long long idx = (long long)blockIdx.x * 256 + threadIdx.x;
  int c = (int)((idx >> 14) & 255);
  int b = (int)(idx >> 22);
  int bg = b * 32 + (c >> 3);
  float mu = stats[bg * 2], rstd = stats[bg * 2 + 1];
  y[idx] = (y[idx] - mu) * rstd * gg[c] + gb[c];
}

// ============================================================================

extern "C" void kernel_launch(void* const* d_in, const int* in_sizes, int n_in,
                              void* d_out, int out_size, void* d_ws, size_t ws_size,
                              hipStream_t stream) {
  const float* feat_3 = (const float*)d_in[1];
  const float* feat_4 = (const float*)d_in[2];
  const float* feat_5 = (const float*)d_in[3];
  const float* w_off5 = (const float*)d_in[4];
  const float* w_om5  = (const float*)d_in[5];
  const float* b_om5  = (const float*)d_in[6];
  const float* w_dcn5 = (const float*)d_in[7];
  const float* b_dcn5 = (const float*)d_in[8];
  const float* w_c1   = (const float*)d_in[9];
  const float* w_off4 = (const float*)d_in[10];
  const float* w_om4  = (const float*)d_in[11];
  const float* b_om4  = (const float*)d_in[12];
  const float* w_dcn4 = (const float*)d_in[13];
  const float* b_dcn4 = (const float*)d_in[14];
  const float* w_sa   = (const float*)d_in[15];
  const float* bn_g   = (const float*)d_in[16];
  const float* bn_b   = (const float*)d_in[17];
  const float* bn_m   = (const float*)d_in[18];
  const float* bn_v   = (const float*)d_in[19];
  const float* w_sem  = (const float*)d_in[20];
  const float* gn_g   = (const float*)d_in[21];
  const float* gn_b   = (const float*)d_in[22];
  float* out = (float*)d_out;
  float* ws = (float*)d_ws;

  // ---- workspace layout (floats); aliases noted ----
  const long long o_T    = 0;                        // 2,883,584 transposed weights
  const long long o_up5  = o_T + 2883584;            // 1,048,576 (alias later: am/sa/gnstats)
  const long long o_off5 = o_up5 + 1048576;          // 1,048,576
  const long long o_om5  = o_off5 + 1048576;         // 884,736
  const long long o_a5   = o_om5 + 884736;           // 1,048,576
  const long long o_f4n  = o_a5 + 1048576;           // 1,048,576
  const long long o_up4  = o_f4n + 1048576;          // 4,194,304 (alias later: z64)
  const long long o_off4 = o_up4 + 4194304;          // 4,194,304 (alias later: f4a)
  const long long o_om4  = o_off4 + 4194304;         // 3,538,944
  const long long o_sh   = o_om4 + 3538944;          // shared: cat / col / f3c

  const long long colAll = 4LL * 2304 * 4096;        // 37,748,736
  const long long colPB  = 2304LL * 4096;            //  9,437,184
  bool allb = ws_size >= (size_t)(o_sh + colAll) * 4;

  float* wT_off5 = ws + o_T;
  float* wT_dcn5 = wT_off5 + 131072;
  float* wT_c1   = wT_dcn5 + 589824;
  float* wT_off4 = wT_c1 + 131072;
  float* wT_dcn4 = wT_off4 + 131072;
  float* wT_sem  = wT_dcn4 + 589824;
  float* wTp_om5 = wT_sem + 131072;   // [2304][256] padded
  float* wTp_om4 = wTp_om5 + 589824;  // [2304][256] padded
  float* up5  = ws + o_up5;
  float* off5 = ws + o_off5;
  float* om5  = ws + o_om5;
  float* a5   = ws + o_a5;
  float* f4n  = ws + o_f4n;
  float* up4  = ws + o_up4;
  float* off4 = ws + o_off4;
  float* om4  = ws + o_om4;
  float* shared = ws + o_sh;
  float* f4a  = off4;               // alias (off4 dead after convgemm om4)
  float* z64  = up4;                // alias (up4 dead after col4 build)
  float* am   = up5;                // alias (up5 dead after col5 build)
  float* sa   = am + 131072;
  float* gnst = sa + 65536;

  dim3 blk(256);

  // ---- transpose all GEMM weights ----
  transpose_kernel<<<cdiv(256LL * 512, 256), blk, 0, stream>>>(w_off5, wT_off5, 256, 512);
  transpose_kernel<<<cdiv(256LL * 2304, 256), blk, 0, stream>>>(w_dcn5, wT_dcn5, 256, 2304);
  transpose_kernel<<<cdiv(256LL * 512, 256), blk, 0, stream>>>(w_c1, wT_c1, 256, 512);
  transpose_kernel<<<cdiv(256LL * 512, 256), blk, 0, stream>>>(w_off4, wT_off4, 256, 512);
  transpose_kernel<<<cdiv(256LL * 2304, 256), blk, 0, stream>>>(w_dcn4, wT_dcn4, 256, 2304);
  transpose_kernel<<<cdiv(256LL * 512, 256), blk, 0, stream>>>(w_sem, wT_sem, 256, 512);
  transpose_pad_kernel<<<cdiv(256LL * 2304, 256), blk, 0, stream>>>(w_om5, wTp_om5, 216, 2304, 256);
  transpose_pad_kernel<<<cdiv(256LL * 2304, 256), blk, 0, stream>>>(w_om4, wTp_om4, 216, 2304, 256);

  // ---- stage A (32x32) ----
  upsample2x_kernel<<<cdiv(1024LL * 32 * 32, 256), blk, 0, stream>>>(feat_5, up5, 1024, 16, 16);
  concat_kernel<<<cdiv(4LL * 512 * 1024, 256), blk, 0, stream>>>(feat_4, up5, shared, 256, 256, 1024, 2.f);
  gemm_kernel<0><<<dim3(8, 2, 4), blk, 0, stream>>>(wT_off5, shared, off5, nullptr,
                                                    256, 1024, 512, 512LL * 1024, 256LL * 1024);
  convgemm_kernel<5><<<dim3(8, 2, 4), blk, 0, stream>>>(wTp_om5, off5, om5, b_om5, 1024);
  dcn_col_kernel<<<dim3(4, 72, 4), blk, 0, stream>>>(up5, om5, shared, 32, 32, 0);
  gemm_kernel<1><<<dim3(8, 2, 4), blk, 0, stream>>>(wT_dcn5, shared, a5, b_dcn5,
                                                    256, 1024, 2304, 2304LL * 1024, 256LL * 1024);
  concat_kernel<<<cdiv(4LL * 512 * 1024, 256), blk, 0, stream>>>(a5, feat_4, shared, 256, 256, 1024, 1.f);
  gemm_kernel<0><<<dim3(8, 2, 4), blk, 0, stream>>>(wT_c1, shared, f4n, nullptr,
                                                    256, 1024, 512, 512LL * 1024, 256LL * 1024);

  // ---- stage B (64x64) ----
  upsample2x_kernel<<<cdiv(1024LL * 64 * 64, 256), blk, 0, stream>>>(f4n, up4, 1024, 32, 32);
  concat_kernel<<<cdiv(4LL * 512 * 4096, 256), blk, 0, stream>>>(feat_3, up4, shared, 256, 256, 4096, 2.f);
  gemm_kernel<0><<<dim3(32, 2, 4), blk, 0, stream>>>(wT_off4, shared, off4, nullptr,
                                                     256, 4096, 512, 512LL * 4096, 256LL * 4096);
  convgemm_kernel<6><<<dim3(32, 2, 4), blk, 0, stream>>>(wTp_om4, off4, om4, b_om4, 4096);
  if (allb) {
    dcn_col_kernel<<<dim3(16, 72, 4), blk, 0, stream>>>(up4, om4, shared, 64, 64, 0);
    gemm_kernel<1><<<dim3(32, 2, 4), blk, 0, stream>>>(wT_dcn4, shared, f4a, b_dcn4,
                                                       256, 4096, 2304, colPB, 256LL * 4096);
  } else {
    for (int b = 0; b < 4; b++) {
      dcn_col_kernel<<<dim3(16, 72, 1), blk, 0, stream>>>(up4, om4, shared, 64, 64, b);
      gemm_kernel<1><<<dim3(32, 2, 1), blk, 0, stream>>>(wT_dcn4, shared, f4a + (long long)b * 256 * 4096,
                                                         b_dcn4, 256, 4096, 2304, 0, 0);
    }
  }
  concat_kernel<<<cdiv(4LL * 512 * 4096, 256), blk, 0, stream>>>(f4a, feat_3, shared, 256, 256, 4096, 1.f);

  // ---- SEM head ----
  avgmax_kernel<<<256, blk, 0, stream>>>(shared, am);
  sa_kernel<<<256, blk, 0, stream>>>(am, w_sa, bn_g, bn_b, bn_m, bn_v, sa);
  gemm_kernel<0><<<dim3(32, 2, 4), blk, 0, stream>>>(wT_sem, shared, z64, nullptr,
                                                     256, 4096, 512, 512LL * 4096, 256LL * 4096);
  final_y_kernel<<<65536, blk, 0, stream>>>(z64, sa, out);
  gn_stats_kernel<<<128, blk, 0, stream>>>(out, gnst);
  gn_apply_kernel<<<65536, blk, 0, stream>>>(out, gnst, gn_g, gn_b);
}

// Round 3
// 1110.244 us; speedup vs baseline: 2.7327x; 2.3224x over previous
//
#include <hip/hip_runtime.h>
#include <math.h>

// ============================================================================
// FeatureAlign (2-level DCNv2 pyramid + SEM head).
// R2: all GEMMs -> MFMA f32_16x16x32_f16, 2-term weight split (W_hi+W_lo) x
//     fp16 activations. Fixes MfmaUtil=0 + 11% occupancy of the fp32 tile GEMM.
// ============================================================================

typedef _Float16 h_t;
typedef _Float16 h2 __attribute__((ext_vector_type(2)));
typedef _Float16 h4 __attribute__((ext_vector_type(4)));
typedef _Float16 h8 __attribute__((ext_vector_type(8)));
typedef float f4 __attribute__((ext_vector_type(4)));

static inline int cdiv(long long a, long long b) { return (int)((a + b - 1) / b); }

// ---------------- weight prep: fp32 [M][K] -> swizzled fp16 hi/lo ----------------
// layout: idx = ((mblk*(K/32)+c)*2 + s)*4096 + m*32 + k   (mblk: 128-row block)
__global__ void prep_w_kernel(const float* __restrict__ W, h_t* __restrict__ Wp,
                              int M, int K) {
  long long idx = (long long)blockIdx.x * 256 + threadIdx.x;
  if (idx >= 512LL * K) return;
  int within = (int)(idx & 4095);
  int m = within >> 5, k = within & 31;
  long long t2 = idx >> 12;
  int s = (int)(t2 & 1);
  long long t3 = t2 >> 1;
  int nck = K >> 5;
  int c = (int)(t3 % nck), mblk = (int)(t3 / nck);
  int gm = mblk * 128 + m, gk = c * 32 + k;
  float f = (gm < M) ? W[(long long)gm * K + gk] : 0.f;
  h_t hi = (h_t)f;
  Wp[idx] = s ? (h_t)(f - (float)hi) : hi;
}

// ---------------- bilinear 2x upsample (half-pixel, edge clamp) ----------------
__global__ void upsample2x_kernel(const float* __restrict__ in, float* __restrict__ out,
                                  int CB, int H, int W) {
  int OH = H * 2, OW = W * 2;
  long long total = (long long)CB * OH * OW;
  long long idx = (long long)blockIdx.x * blockDim.x + threadIdx.x;
  if (idx >= total) return;
  int ow = (int)(idx % OW);
  long long t = idx / OW;
  int oh = (int)(t % OH);
  int cb = (int)(t / OH);
  int iy = oh >> 1, ix = ow >> 1;
  int iy2 = (oh & 1) ? min(iy + 1, H - 1) : max(iy - 1, 0);
  int ix2 = (ow & 1) ? min(ix + 1, W - 1) : max(ix - 1, 0);
  const float* p = in + (long long)cb * H * W;
  out[idx] = 0.5625f * p[iy * W + ix] + 0.1875f * (p[iy * W + ix2] + p[iy2 * W + ix])
           + 0.0625f * p[iy2 * W + ix2];
}

// ---------------- channel concat -> fp16: out[b] = [A[b], scale*B[b]] ----------------
template <typename TA>
__global__ void concat_h_kernel(const TA* __restrict__ A, const float* __restrict__ Bp,
                                h_t* __restrict__ out, int C1, int C2, int HW, float scale) {
  long long idx = (long long)blockIdx.x * blockDim.x + threadIdx.x;
  long long total = 4LL * (C1 + C2) * HW;
  if (idx >= total) return;
  int p = (int)(idx % HW);
  long long t = idx / HW;
  int c = (int)(t % (C1 + C2));
  int b = (int)(t / (C1 + C2));
  float v;
  if (c < C1) v = (float)A[((long long)b * C1 + c) * HW + p];
  else        v = scale * Bp[((long long)b * C2 + (c - C1)) * HW + p];
  out[idx] = (h_t)v;
}

// ---------------- MFMA GEMM: C[z] = (W_hi + W_lo)^split @ B[z] ----------------
// Wp: swizzled fp16 (prep_w). B: fp16 [K][N]. Block tile 128M x 64N, 4 waves
// (2x2), wave tile 64x32. LDS stride 40 halves (b128-aligned, bank-floor).
template <int RELU, int OUTH>
__global__ __launch_bounds__(256) void mgemm_kernel(
    const h_t* __restrict__ Wp, const h_t* __restrict__ B, void* __restrict__ Cv,
    const float* __restrict__ bias, int Mstore, int N, int K,
    long long sB, long long sC) {
  __shared__ __align__(16) h_t Ah[128 * 40];
  __shared__ __align__(16) h_t Al[128 * 40];
  __shared__ __align__(16) h_t Bs[64 * 40];
  const int tid = threadIdx.x;
  const int bn = blockIdx.x * 64;
  const int mblk = blockIdx.y;
  const int z = blockIdx.z;
  const h_t* Bb = B + (long long)z * sB;
  const int nck = K >> 5;
  const h_t* Wt = Wp + (long long)mblk * nck * 8192 + (tid << 5);
  const int wid = tid >> 6, lane = tid & 63;
  const int wm = (wid >> 1) * 64, wn = (wid & 1) * 32;
  const int l15 = lane & 15, q = lane >> 4;
  f4 acc[4][2] = {};
  h_t* Adst = (tid >= 128 ? Al : Ah) + (tid & 127) * 40;
  const int kp = tid >> 4, ngf = tid & 15;
  h_t* Bdst = Bs + ngf * 4 * 40 + kp * 2;
  for (int c = 0; c < nck; ++c) {
    const h_t* asrc = Wt + c * 8192;
#pragma unroll
    for (int i = 0; i < 4; ++i)
      *(h8*)(Adst + i * 8) = *(const h8*)(asrc + i * 8);
    const h_t* bsrc = Bb + (long long)(c * 32 + kp * 2) * N + bn + ngf * 4;
    h4 r0 = *(const h4*)bsrc;
    h4 r1 = *(const h4*)(bsrc + N);
#pragma unroll
    for (int j = 0; j < 4; ++j) {
      h2 v; v.x = r0[j]; v.y = r1[j];
      *(h2*)(Bdst + j * 40) = v;
    }
    __syncthreads();
    h8 bf[2];
#pragma unroll
    for (int nt = 0; nt < 2; ++nt)
      bf[nt] = *(const h8*)(Bs + (wn + nt * 16 + l15) * 40 + q * 8);
#pragma unroll
    for (int mt = 0; mt < 4; ++mt) {
      const int ro = (wm + mt * 16 + l15) * 40 + q * 8;
      h8 ahi = *(const h8*)(Ah + ro);
      h8 alo = *(const h8*)(Al + ro);
#pragma unroll
      for (int nt = 0; nt < 2; ++nt) {
        acc[mt][nt] = __builtin_amdgcn_mfma_f32_16x16x32_f16(ahi, bf[nt], acc[mt][nt], 0, 0, 0);
        acc[mt][nt] = __builtin_amdgcn_mfma_f32_16x16x32_f16(alo, bf[nt], acc[mt][nt], 0, 0, 0);
      }
    }
    __syncthreads();
  }
#pragma unroll
  for (int mt = 0; mt < 4; ++mt)
#pragma unroll
    for (int nt = 0; nt < 2; ++nt) {
      int n = bn + wn + nt * 16 + l15;
#pragma unroll
      for (int r = 0; r < 4; ++r) {
        int row = mblk * 128 + wm + mt * 16 + q * 4 + r;
        if (row < Mstore) {
          float v = acc[mt][nt][r] + (bias ? bias[row] : 0.f);
          if (RELU) v = fmaxf(v, 0.f);
          if (OUTH) ((h_t*)Cv)[(long long)z * sC + (long long)row * N + n] = (h_t)v;
          else      ((float*)Cv)[(long long)z * sC + (long long)row * N + n] = v;
        }
      }
    }
}

// ---------------- conv3x3 as MFMA implicit GEMM (K=2304, M=216 padded) ----------------
// B-tile built from shifted fp16 input rows; out fp32 + bias.
template <int LOGW>
__global__ __launch_bounds__(256) void mconv_kernel(
    const h_t* __restrict__ Wp, const h_t* __restrict__ Off, float* __restrict__ Cf,
    const float* __restrict__ bias, int HW) {
  const int W = 1 << LOGW, H = HW >> LOGW;
  __shared__ __align__(16) h_t Ah[128 * 40];
  __shared__ __align__(16) h_t Al[128 * 40];
  __shared__ __align__(16) h_t Bs[64 * 40];
  const int tid = threadIdx.x;
  const int p0 = blockIdx.x * 64;
  const int mblk = blockIdx.y;
  const int z = blockIdx.z;
  const h_t* Ob = Off + (long long)z * 256 * HW;
  const int nck = 72;  // K=2304
  const h_t* Wt = Wp + (long long)mblk * nck * 8192 + (tid << 5);
  const int wid = tid >> 6, lane = tid & 63;
  const int wm = (wid >> 1) * 64, wn = (wid & 1) * 32;
  const int l15 = lane & 15, q = lane >> 4;
  f4 acc[4][2] = {};
  h_t* Adst = (tid >= 128 ? Al : Ah) + (tid & 127) * 40;
  const int kp = tid >> 4, ngf = tid & 15;
  h_t* Bdst = Bs + ngf * 4 * 40 + kp * 2;
  const int pbase = p0 + ngf * 4;
  const int y = pbase >> LOGW;
  const int x0 = pbase & (W - 1);
  for (int c = 0; c < nck; ++c) {
    const h_t* asrc = Wt + c * 8192;
#pragma unroll
    for (int i = 0; i < 4; ++i)
      *(h8*)(Adst + i * 8) = *(const h8*)(asrc + i * 8);
    h_t tmp[2][4];
#pragma unroll
    for (int kk = 0; kk < 2; ++kk) {
      int k = c * 32 + kp * 2 + kk;
      int ch = k / 9;
      int tap = k - ch * 9;
      int t3 = tap / 3;
      int dy = t3 - 1, dx = tap - t3 * 3 - 1;
      int sy = y + dy;
      bool yok = (sy >= 0) & (sy < H);
      const h_t* src = Ob + (long long)ch * HW + sy * W;
#pragma unroll
      for (int j = 0; j < 4; ++j) {
        int sx = x0 + j + dx;
        h_t v = (h_t)0.f;
        if (yok && sx >= 0 && sx < W) v = src[sx];
        tmp[kk][j] = v;
      }
    }
#pragma unroll
    for (int j = 0; j < 4; ++j) {
      h2 v; v.x = tmp[0][j]; v.y = tmp[1][j];
      *(h2*)(Bdst + j * 40) = v;
    }
    __syncthreads();
    h8 bf[2];
#pragma unroll
    for (int nt = 0; nt < 2; ++nt)
      bf[nt] = *(const h8*)(Bs + (wn + nt * 16 + l15) * 40 + q * 8);
#pragma unroll
    for (int mt = 0; mt < 4; ++mt) {
      const int ro = (wm + mt * 16 + l15) * 40 + q * 8;
      h8 ahi = *(const h8*)(Ah + ro);
      h8 alo = *(const h8*)(Al + ro);
#pragma unroll
      for (int nt = 0; nt < 2; ++nt) {
        acc[mt][nt] = __builtin_amdgcn_mfma_f32_16x16x32_f16(ahi, bf[nt], acc[mt][nt], 0, 0, 0);
        acc[mt][nt] = __builtin_amdgcn_mfma_f32_16x16x32_f16(alo, bf[nt], acc[mt][nt], 0, 0, 0);
      }
    }
    __syncthreads();
  }
  float* Cb = Cf + (long long)z * 216 * HW;
#pragma unroll
  for (int mt = 0; mt < 4; ++mt)
#pragma unroll
    for (int nt = 0; nt < 2; ++nt) {
      int n = p0 + wn + nt * 16 + l15;
#pragma unroll
      for (int r = 0; r < 4; ++r) {
        int row = mblk * 128 + wm + mt * 16 + q * 4 + r;
        if (row < 216)
          Cb[(long long)row * HW + n] = acc[mt][nt][r] + bias[row];
      }
    }
}

// ---------------- DCNv2 column build (fp16 out): col[bz][(g*32+c)*9+k][p] ----------------
__global__ void dcn_col_kernel(const float* __restrict__ x, const float* __restrict__ om,
                               h_t* __restrict__ col, int H, int W, int b0) {
  int HW = H * W;
  int p = blockIdx.x * 256 + threadIdx.x;
  int gk = blockIdx.y;           // 0..71
  int g = gk / 9, k9 = gk - g * 9;
  int bz = blockIdx.z;
  int b = b0 + bz;
  int h = p / W, wc = p - h * W;
  const float* omb = om + (long long)b * 216 * HW;
  float offy = omb[(long long)gk * HW + p];
  float offx = omb[(long long)(72 + gk) * HW + p];
  float mraw = omb[(long long)(144 + gk) * HW + p];
  float mask = 1.f / (1.f + expf(-mraw));
  float y = (float)h + (float)(k9 / 3 - 1) + offy;
  float xx = (float)wc + (float)(k9 % 3 - 1) + offx;
  float y0f = floorf(y), x0f = floorf(xx);
  int y0 = (int)y0f, x0 = (int)x0f;
  float fy = y - y0f, fx = xx - x0f;
  float w00 = (1.f - fy) * (1.f - fx), w01 = (1.f - fy) * fx;
  float w10 = fy * (1.f - fx), w11 = fy * fx;
  bool iy0 = (y0 >= 0) & (y0 < H), iy1 = (y0 + 1 >= 0) & (y0 + 1 < H);
  bool ix0 = (x0 >= 0) & (x0 < W), ix1 = (x0 + 1 >= 0) & (x0 + 1 < W);
  w00 = (iy0 & ix0) ? w00 : 0.f;
  w01 = (iy0 & ix1) ? w01 : 0.f;
  w10 = (iy1 & ix0) ? w10 : 0.f;
  w11 = (iy1 & ix1) ? w11 : 0.f;
  int y0c = min(max(y0, 0), H - 1), y1c = min(max(y0 + 1, 0), H - 1);
  int x0c = min(max(x0, 0), W - 1), x1c = min(max(x0 + 1, 0), W - 1);
  int i00 = y0c * W + x0c, i01 = y0c * W + x1c, i10 = y1c * W + x0c, i11 = y1c * W + x1c;
  const float* xb = x + ((long long)b * 256 + g * 32) * HW;
  h_t* cb = col + ((long long)bz * 2304 + (long long)(g * 32) * 9 + k9) * HW + p;
#pragma unroll 4
  for (int c = 0; c < 32; c++) {
    const float* xc = xb + (long long)c * HW;
    float v = w00 * xc[i00] + w01 * xc[i01] + w10 * xc[i10] + w11 * xc[i11];
    cb[(long long)c * 9 * HW] = (h_t)(v * mask);
  }
}

// ---------------- channel avg/max of up2x(f3c fp16) at 128x128 ----------------
__global__ void avgmax_kernel(const h_t* __restrict__ f3c, float* __restrict__ am) {
  int idx = blockIdx.x * 256 + threadIdx.x; // 4*16384
  int b = idx >> 14, p = idx & 16383;
  int oh = p >> 7, ow = p & 127;
  int iy = oh >> 1, ix = ow >> 1;
  int iy2 = (oh & 1) ? min(iy + 1, 63) : max(iy - 1, 0);
  int ix2 = (ow & 1) ? min(ix + 1, 63) : max(ix - 1, 0);
  int i00 = iy * 64 + ix, i01 = iy * 64 + ix2, i10 = iy2 * 64 + ix, i11 = iy2 * 64 + ix2;
  const h_t* base = f3c + (long long)b * 512 * 4096;
  float sum = 0.f, mx = -3.4e38f;
  for (int c = 0; c < 512; c++) {
    const h_t* pc = base + (long long)c * 4096;
    float v = 0.5625f * (float)pc[i00] + 0.1875f * ((float)pc[i01] + (float)pc[i10])
            + 0.0625f * (float)pc[i11];
    sum += v;
    mx = fmaxf(mx, v);
  }
  am[(long long)b * 2 * 16384 + p] = sum * (1.f / 512.f);
  am[(long long)b * 2 * 16384 + 16384 + p] = mx;
}

// ---------------- conv7x7 (2->1) + BN + sigmoid -> sa ----------------
__global__ void sa_kernel(const float* __restrict__ am, const float* __restrict__ w_sa,
                          const float* __restrict__ bn_g, const float* __restrict__ bn_b,
                          const float* __restrict__ bn_m, const float* __restrict__ bn_v,
                          float* __restrict__ sa) {
  int idx = blockIdx.x * 256 + threadIdx.x; // 4*16384
  int b = idx >> 14, p = idx & 16383;
  int oh = p >> 7, ow = p & 127;
  float acc = 0.f;
  for (int ci = 0; ci < 2; ci++) {
    const float* base = am + ((long long)b * 2 + ci) * 16384;
    for (int dy = 0; dy < 7; dy++) {
      int yy = oh + dy - 3;
      if (yy < 0 || yy > 127) continue;
      for (int dx = 0; dx < 7; dx++) {
        int xx = ow + dx - 3;
        if (xx < 0 || xx > 127) continue;
        acc += w_sa[ci * 49 + dy * 7 + dx] * base[yy * 128 + xx];
      }
    }
  }
  float a = (acc - bn_m[0]) * rsqrtf(bn_v[0] + 1e-5f);
  a = a * bn_g[0] + bn_b[0];
  sa[idx] = 1.f / (1.f + expf(-a));
}

// ---------------- y = (1+sa) * up2x(z) ----------------
__global__ void final_y_kernel(const float* __restrict__ z, const float* __restrict__ sa,
                               float* __restrict__ out) {
  long long idx = (long long)blockIdx.x * 256 + threadIdx.x; // 16,777,216
  int ow = (int)(idx & 127);
  long long t = idx >> 7;
  int oh = (int)(t & 127);
  t >>= 7;
  int c = (int)(t & 255);
  int b = (int)(t >> 8);
  int iy = oh >> 1, ix = ow >> 1;
  int iy2 = (oh & 1) ? min(iy + 1, 63) : max(iy - 1, 0);
  int ix2 = (ow & 1) ? min(ix + 1, 63) : max(ix - 1, 0);
  const float* zp = z + (long long)(b * 256 + c) * 4096;
  float v = 0.5625f * zp[iy * 64 + ix] + 0.1875f * (zp[iy * 64 + ix2] + zp[iy2 * 64 + ix])
          + 0.0625f * zp[iy2 * 64 + ix2];
  float s = sa[((long long)b << 14) + (oh << 7) + ow];
  out[idx] = v * (1.f + s);
}

// ---------------- GroupNorm (32 groups over 256ch) ----------------
__global__ __launch_bounds__(256) void gn_stats_kernel(const float* __restrict__ y,
                                                       float* __restrict__ stats) {
  int bg = blockIdx.x; // 0..127
  int b = bg >> 5, g = bg & 31;
  const float* base = y + ((long long)b * 256 + g * 8) * 16384;
  float s = 0.f, ss = 0.f;
  for (int i = threadIdx.x; i < 8 * 16384; i += 256) {
    float v = base[i];
    s += v;
    ss += v * v;
  }
#pragma unroll
  for (int off = 32; off > 0; off >>= 1) {
    s += __shfl_down(s, off);
    ss += __shfl_down(ss, off);
  }
  __shared__ float rs[2][4];
  int lane = threadIdx.x & 63, wv = threadIdx.x >> 6;
  if (lane == 0) { rs[0][wv] = s; rs[1][wv] = ss; }
  __syncthreads();
  if (threadIdx.x == 0) {
    float S = rs[0][0] + rs[0][1] + rs[0][2] + rs[0][3];
    float SS = rs[1][0] + rs[1][1] + rs[1][2] + rs[1][3];
    float n = 8.f * 16384.f;
    float mu = S / n;
    float var = SS / n - mu * mu;
    stats[bg * 2] = mu;
    stats[bg * 2 + 1] = rsqrtf(var + 1e-5f);
  }
}

__global__ void gn_apply_kernel(float* __restrict__ y, const float* __restrict__ stats,
                                const float* __restrict__ gg, const float* __restrict__ gb) {
  long long idx = (long long)blockIdx.x * 256 + threadIdx.x;
  int c = (int)((idx >> 14) & 255);
  int b = (int)(idx >> 22);
  int bg = b * 32 + (c >> 3);
  float mu = stats[bg * 2], rstd = stats[bg * 2 + 1];
  y[idx] = (y[idx] - mu) * rstd * gg[c] + gb[c];
}

// ============================================================================

extern "C" void kernel_launch(void* const* d_in, const int* in_sizes, int n_in,
                              void* d_out, int out_size, void* d_ws, size_t ws_size,
                              hipStream_t stream) {
  const float* feat_3 = (const float*)d_in[1];
  const float* feat_4 = (const float*)d_in[2];
  const float* feat_5 = (const float*)d_in[3];
  const float* w_off5 = (const float*)d_in[4];
  const float* w_om5  = (const float*)d_in[5];
  const float* b_om5  = (const float*)d_in[6];
  const float* w_dcn5 = (const float*)d_in[7];
  const float* b_dcn5 = (const float*)d_in[8];
  const float* w_c1   = (const float*)d_in[9];
  const float* w_off4 = (const float*)d_in[10];
  const float* w_om4  = (const float*)d_in[11];
  const float* b_om4  = (const float*)d_in[12];
  const float* w_dcn4 = (const float*)d_in[13];
  const float* b_dcn4 = (const float*)d_in[14];
  const float* w_sa   = (const float*)d_in[15];
  const float* bn_g   = (const float*)d_in[16];
  const float* bn_b   = (const float*)d_in[17];
  const float* bn_m   = (const float*)d_in[18];
  const float* bn_v   = (const float*)d_in[19];
  const float* w_sem  = (const float*)d_in[20];
  const float* gn_g   = (const float*)d_in[21];
  const float* gn_b   = (const float*)d_in[22];
  float* out = (float*)d_out;
  float* ws = (float*)d_ws;

  // ---- workspace (float offsets) ----
  const long long o_Wp    = 0;                       // 2,883,584 f (fp16 weights)
  const long long o_up5   = o_Wp + 2883584;          // 1,048,576 (alias: am/sa/gnst)
  const long long o_off5h = o_up5 + 1048576;         //   524,288 (fp16)
  const long long o_om5   = o_off5h + 524288;        //   884,736
  const long long o_a5    = o_om5 + 884736;          // 1,048,576
  const long long o_f4n   = o_a5 + 1048576;          // 1,048,576
  const long long o_up4   = o_f4n + 1048576;         // 4,194,304 (alias: z64)
  const long long o_off4h = o_up4 + 4194304;         // 2,097,152 (fp16; alias f4a fp16)
  const long long o_om4   = o_off4h + 2097152;       // 3,538,944
  const long long o_sh    = o_om4 + 3538944;         // shared: cat/col/f3c (fp16)

  const long long shAll = 18874368;                  // col4 all-batch (fp16, floats)
  const long long shPB  = 4718592;                   // col per-batch
  bool allb = ws_size >= (size_t)(o_sh + shAll) * 4;

  h_t* WpH = (h_t*)ws;
  h_t* wp_off5 = WpH;
  h_t* wp_dcn5 = wp_off5 + 262144;
  h_t* wp_c1   = wp_dcn5 + 1179648;
  h_t* wp_om5  = wp_c1 + 262144;
  h_t* wp_off4 = wp_om5 + 1179648;
  h_t* wp_dcn4 = wp_off4 + 262144;
  h_t* wp_om4  = wp_dcn4 + 1179648;
  h_t* wp_sem  = wp_om4 + 1179648;

  float* up5   = ws + o_up5;
  h_t*   off5h = (h_t*)(ws + o_off5h);
  float* om5   = ws + o_om5;
  float* a5    = ws + o_a5;
  float* f4n   = ws + o_f4n;
  float* up4   = ws + o_up4;
  h_t*   off4h = (h_t*)(ws + o_off4h);
  float* om4   = ws + o_om4;
  h_t*   shH   = (h_t*)(ws + o_sh);
  h_t*   f4aH  = off4h;             // alias (off4 dead after mconv om4)
  float* z64   = up4;               // alias (up4 dead after col4 build)
  float* am    = up5;               // alias (up5 dead after col5 build)
  float* sa    = am + 131072;
  float* gnst  = sa + 65536;

  dim3 blk(256);

  // ---- weight prep (fp16 hi/lo, swizzled) ----
  prep_w_kernel<<<cdiv(512LL * 512, 256), blk, 0, stream>>>(w_off5, wp_off5, 256, 512);
  prep_w_kernel<<<cdiv(512LL * 2304, 256), blk, 0, stream>>>(w_dcn5, wp_dcn5, 256, 2304);
  prep_w_kernel<<<cdiv(512LL * 512, 256), blk, 0, stream>>>(w_c1, wp_c1, 256, 512);
  prep_w_kernel<<<cdiv(512LL * 2304, 256), blk, 0, stream>>>(w_om5, wp_om5, 216, 2304);
  prep_w_kernel<<<cdiv(512LL * 512, 256), blk, 0, stream>>>(w_off4, wp_off4, 256, 512);
  prep_w_kernel<<<cdiv(512LL * 2304, 256), blk, 0, stream>>>(w_dcn4, wp_dcn4, 256, 2304);
  prep_w_kernel<<<cdiv(512LL * 2304, 256), blk, 0, stream>>>(w_om4, wp_om4, 216, 2304);
  prep_w_kernel<<<cdiv(512LL * 512, 256), blk, 0, stream>>>(w_sem, wp_sem, 256, 512);

  // ---- stage A (32x32, HW=1024) ----
  upsample2x_kernel<<<cdiv(1024LL * 1024, 256), blk, 0, stream>>>(feat_5, up5, 1024, 16, 16);
  concat_h_kernel<float><<<cdiv(4LL * 512 * 1024, 256), blk, 0, stream>>>(
      feat_4, up5, shH, 256, 256, 1024, 2.f);
  mgemm_kernel<0, 1><<<dim3(16, 2, 4), blk, 0, stream>>>(
      wp_off5, shH, off5h, nullptr, 256, 1024, 512, 512LL * 1024, 256LL * 1024);
  mconv_kernel<5><<<dim3(16, 2, 4), blk, 0, stream>>>(wp_om5, off5h, om5, b_om5, 1024);
  dcn_col_kernel<<<dim3(4, 72, 4), blk, 0, stream>>>(up5, om5, shH, 32, 32, 0);
  mgemm_kernel<1, 0><<<dim3(16, 2, 4), blk, 0, stream>>>(
      wp_dcn5, shH, a5, b_dcn5, 256, 1024, 2304, 2304LL * 1024, 256LL * 1024);
  concat_h_kernel<float><<<cdiv(4LL * 512 * 1024, 256), blk, 0, stream>>>(
      a5, feat_4, shH, 256, 256, 1024, 1.f);
  mgemm_kernel<0, 0><<<dim3(16, 2, 4), blk, 0, stream>>>(
      wp_c1, shH, f4n, nullptr, 256, 1024, 512, 512LL * 1024, 256LL * 1024);

  // ---- stage B (64x64, HW=4096) ----
  upsample2x_kernel<<<cdiv(4194304LL, 256), blk, 0, stream>>>(f4n, up4, 1024, 32, 32);
  concat_h_kernel<float><<<cdiv(4LL * 512 * 4096, 256), blk, 0, stream>>>(
      feat_3, up4, shH, 256, 256, 4096, 2.f);
  mgemm_kernel<0, 1><<<dim3(64, 2, 4), blk, 0, stream>>>(
      wp_off4, shH, off4h, nullptr, 256, 4096, 512, 512LL * 4096, 256LL * 4096);
  mconv_kernel<6><<<dim3(64, 2, 4), blk, 0, stream>>>(wp_om4, off4h, om4, b_om4, 4096);
  if (allb) {
    dcn_col_kernel<<<dim3(16, 72, 4), blk, 0, stream>>>(up4, om4, shH, 64, 64, 0);
    mgemm_kernel<1, 1><<<dim3(64, 2, 4), blk, 0, stream>>>(
        wp_dcn4, shH, f4aH, b_dcn4, 256, 4096, 2304, 2304LL * 4096, 256LL * 4096);
  } else {
    for (int b = 0; b < 4; b++) {
      dcn_col_kernel<<<dim3(16, 72, 1), blk, 0, stream>>>(up4, om4, shH, 64, 64, b);
      mgemm_kernel<1, 1><<<dim3(64, 2, 1), blk, 0, stream>>>(
          wp_dcn4, shH, f4aH + (long long)b * 1048576, b_dcn4, 256, 4096, 2304, 0, 0);
    }
  }
  concat_h_kernel<h_t><<<cdiv(4LL * 512 * 4096, 256), blk, 0, stream>>>(
      f4aH, feat_3, shH, 256, 256, 4096, 1.f);

  // ---- SEM head ----
  avgmax_kernel<<<256, blk, 0, stream>>>(shH, am);
  sa_kernel<<<256, blk, 0, stream>>>(am, w_sa, bn_g, bn_b, bn_m, bn_v, sa);
  mgemm_kernel<0, 0><<<dim3(64, 2, 4), blk, 0, stream>>>(
      wp_sem, shH, z64, nullptr, 256, 4096, 512, 512LL * 4096, 256LL * 4096);
  final_y_kernel<<<65536, blk, 0, stream>>>(z64, sa, out);
  gn_stats_kernel<<<128, blk, 0, stream>>>(out, gnst);
  gn_apply_kernel<<<65536, blk, 0, stream>>>(out, gnst, gn_g, gn_b);
}

// Round 4
// 886.892 us; speedup vs baseline: 3.4209x; 1.2518x over previous
//
#include <hip/hip_runtime.h>
#include <math.h>

// ============================================================================
// FeatureAlign (2-level DCNv2 pyramid + SEM head).
// R3: GN stats fused into final_y (was 150us @ 0.5 block/CU); offset/mask-path
//     GEMMs single fp16 term; mconv tap-major (no per-element k div-mod);
//     wider avgmax/sa grids; vectorized gn_apply.
// ============================================================================

typedef _Float16 h_t;
typedef _Float16 h2 __attribute__((ext_vector_type(2)));
typedef _Float16 h4 __attribute__((ext_vector_type(4)));
typedef _Float16 h8 __attribute__((ext_vector_type(8)));
typedef float f4 __attribute__((ext_vector_type(4)));

static inline int cdiv(long long a, long long b) { return (int)((a + b - 1) / b); }

// ---------------- weight prep: fp32 [M][K] -> swizzled fp16 hi/lo ----------------
// layout: idx = ((mblk*(K/32)+c)*2 + s)*4096 + m*32 + k   (mblk: 128-row block)
// PERM=1: k-space permuted tap-major for conv3x3 weights: k' = tap*256 + ch,
//         source k = ch*9 + tap  (K must be 2304).
template <int PERM>
__global__ void prep_w_kernel(const float* __restrict__ W, h_t* __restrict__ Wp,
                              int M, int K) {
  long long idx = (long long)blockIdx.x * 256 + threadIdx.x;
  if (idx >= 512LL * K) return;
  int within = (int)(idx & 4095);
  int m = within >> 5, k = within & 31;
  long long t2 = idx >> 12;
  int s = (int)(t2 & 1);
  long long t3 = t2 >> 1;
  int nck = K >> 5;
  int c = (int)(t3 % nck), mblk = (int)(t3 / nck);
  int gm = mblk * 128 + m, gk = c * 32 + k;
  if (PERM) gk = (gk & 255) * 9 + (gk >> 8);
  float f = (gm < M) ? W[(long long)gm * K + gk] : 0.f;
  h_t hi = (h_t)f;
  Wp[idx] = s ? (h_t)(f - (float)hi) : hi;
}

// ---------------- bilinear 2x upsample (half-pixel, edge clamp) ----------------
__global__ void upsample2x_kernel(const float* __restrict__ in, float* __restrict__ out,
                                  int CB, int H, int W) {
  int OH = H * 2, OW = W * 2;
  long long total = (long long)CB * OH * OW;
  long long idx = (long long)blockIdx.x * blockDim.x + threadIdx.x;
  if (idx >= total) return;
  int ow = (int)(idx % OW);
  long long t = idx / OW;
  int oh = (int)(t % OH);
  int cb = (int)(t / OH);
  int iy = oh >> 1, ix = ow >> 1;
  int iy2 = (oh & 1) ? min(iy + 1, H - 1) : max(iy - 1, 0);
  int ix2 = (ow & 1) ? min(ix + 1, W - 1) : max(ix - 1, 0);
  const float* p = in + (long long)cb * H * W;
  out[idx] = 0.5625f * p[iy * W + ix] + 0.1875f * (p[iy * W + ix2] + p[iy2 * W + ix])
           + 0.0625f * p[iy2 * W + ix2];
}

// ---------------- channel concat -> fp16: out[b] = [A[b], scale*B[b]] ----------------
template <typename TA>
__global__ void concat_h_kernel(const TA* __restrict__ A, const float* __restrict__ Bp,
                                h_t* __restrict__ out, int C1, int C2, int HW, float scale) {
  long long idx = (long long)blockIdx.x * blockDim.x + threadIdx.x;
  long long total = 4LL * (C1 + C2) * HW;
  if (idx >= total) return;
  int p = (int)(idx % HW);
  long long t = idx / HW;
  int c = (int)(t % (C1 + C2));
  int b = (int)(t / (C1 + C2));
  float v;
  if (c < C1) v = (float)A[((long long)b * C1 + c) * HW + p];
  else        v = scale * Bp[((long long)b * C2 + (c - C1)) * HW + p];
  out[idx] = (h_t)v;
}

// ---------------- MFMA GEMM: C[z] = W @ B[z], optional 2-term split ----------------
// Wp: swizzled fp16 (prep_w). B: fp16 [K][N]. Block tile 128M x 64N, 4 waves
// (2x2), wave tile 64x32. LDS stride 40 halves. TWO=1: W_hi+W_lo split.
template <int RELU, int OUTH, int TWO>
__global__ __launch_bounds__(256) void mgemm_kernel(
    const h_t* __restrict__ Wp, const h_t* __restrict__ B, void* __restrict__ Cv,
    const float* __restrict__ bias, int Mstore, int N, int K,
    long long sB, long long sC) {
  __shared__ __align__(16) h_t Ah[128 * 40];
  __shared__ __align__(16) h_t Al[TWO ? 128 * 40 : 8];
  __shared__ __align__(16) h_t Bs[64 * 40];
  const int tid = threadIdx.x;
  const int bn = blockIdx.x * 64;
  const int mblk = blockIdx.y;
  const int z = blockIdx.z;
  const h_t* Bb = B + (long long)z * sB;
  const int nck = K >> 5;
  const h_t* Wt = Wp + (long long)mblk * nck * 8192 +
                  (TWO ? (tid << 5) : ((tid >> 1) << 5) + ((tid & 1) << 4));
  const int wid = tid >> 6, lane = tid & 63;
  const int wm = (wid >> 1) * 64, wn = (wid & 1) * 32;
  const int l15 = lane & 15, q = lane >> 4;
  f4 acc[4][2] = {};
  h_t* Adst = TWO ? (tid >= 128 ? Al : Ah) + (tid & 127) * 40
                  : Ah + (tid >> 1) * 40 + ((tid & 1) << 4);
  const int kp = tid >> 4, ngf = tid & 15;
  h_t* Bdst = Bs + ngf * 4 * 40 + kp * 2;
  for (int c = 0; c < nck; ++c) {
    const h_t* asrc = Wt + c * 8192;
    if (TWO) {
#pragma unroll
      for (int i = 0; i < 4; ++i)
        *(h8*)(Adst + i * 8) = *(const h8*)(asrc + i * 8);
    } else {
      *(h8*)(Adst) = *(const h8*)(asrc);
      *(h8*)(Adst + 8) = *(const h8*)(asrc + 8);
    }
    const h_t* bsrc = Bb + (long long)(c * 32 + kp * 2) * N + bn + ngf * 4;
    h4 r0 = *(const h4*)bsrc;
    h4 r1 = *(const h4*)(bsrc + N);
#pragma unroll
    for (int j = 0; j < 4; ++j) {
      h2 v; v.x = r0[j]; v.y = r1[j];
      *(h2*)(Bdst + j * 40) = v;
    }
    __syncthreads();
    h8 bf[2];
#pragma unroll
    for (int nt = 0; nt < 2; ++nt)
      bf[nt] = *(const h8*)(Bs + (wn + nt * 16 + l15) * 40 + q * 8);
#pragma unroll
    for (int mt = 0; mt < 4; ++mt) {
      const int ro = (wm + mt * 16 + l15) * 40 + q * 8;
      h8 ahi = *(const h8*)(Ah + ro);
#pragma unroll
      for (int nt = 0; nt < 2; ++nt)
        acc[mt][nt] = __builtin_amdgcn_mfma_f32_16x16x32_f16(ahi, bf[nt], acc[mt][nt], 0, 0, 0);
      if (TWO) {
        h8 alo = *(const h8*)(Al + ro);
#pragma unroll
        for (int nt = 0; nt < 2; ++nt)
          acc[mt][nt] = __builtin_amdgcn_mfma_f32_16x16x32_f16(alo, bf[nt], acc[mt][nt], 0, 0, 0);
      }
    }
    __syncthreads();
  }
#pragma unroll
  for (int mt = 0; mt < 4; ++mt)
#pragma unroll
    for (int nt = 0; nt < 2; ++nt) {
      int n = bn + wn + nt * 16 + l15;
#pragma unroll
      for (int r = 0; r < 4; ++r) {
        int row = mblk * 128 + wm + mt * 16 + q * 4 + r;
        if (row < Mstore) {
          float v = acc[mt][nt][r] + (bias ? bias[row] : 0.f);
          if (RELU) v = fmaxf(v, 0.f);
          if (OUTH) ((h_t*)Cv)[(long long)z * sC + (long long)row * N + n] = (h_t)v;
          else      ((float*)Cv)[(long long)z * sC + (long long)row * N + n] = v;
        }
      }
    }
}

// ---------------- conv3x3 as MFMA implicit GEMM, tap-major K ----------------
// Wp: prep_w<PERM=1> layout, k' = tap*256+ch. Single fp16 term (hi only).
// Outer loop tap (dy,dx wave-uniform), inner 8 chunks of 32 channels.
template <int LOGW>
__global__ __launch_bounds__(256) void mconv_kernel(
    const h_t* __restrict__ Wp, const h_t* __restrict__ Off, float* __restrict__ Cf,
    const float* __restrict__ bias, int HW) {
  const int W = 1 << LOGW, H = HW >> LOGW;
  __shared__ __align__(16) h_t Ah[128 * 40];
  __shared__ __align__(16) h_t Bs[64 * 40];
  const int tid = threadIdx.x;
  const int p0 = blockIdx.x * 64;
  const int mblk = blockIdx.y;
  const int z = blockIdx.z;
  const h_t* Ob = Off + (long long)z * 256 * HW;
  const h_t* Wt = Wp + (long long)mblk * 72 * 8192 + ((tid >> 1) << 5) + ((tid & 1) << 4);
  const int wid = tid >> 6, lane = tid & 63;
  const int wm = (wid >> 1) * 64, wn = (wid & 1) * 32;
  const int l15 = lane & 15, q = lane >> 4;
  f4 acc[4][2] = {};
  h_t* Adst = Ah + (tid >> 1) * 40 + ((tid & 1) << 4);
  const int kp = tid >> 4, ngf = tid & 15;
  h_t* Bdst = Bs + ngf * 4 * 40 + kp * 2;
  int py[4], px[4];
#pragma unroll
  for (int j = 0; j < 4; ++j) {
    int p = p0 + ngf * 4 + j;
    py[j] = p >> LOGW;
    px[j] = p & (W - 1);
  }
  for (int tap = 0; tap < 9; ++tap) {
    const int dy = tap / 3 - 1, dx = tap - (tap / 3) * 3 - 1;
#pragma unroll 1
    for (int c2 = 0; c2 < 8; ++c2) {
      const int c = tap * 8 + c2;
      const h_t* asrc = Wt + c * 8192;
      *(h8*)(Adst) = *(const h8*)(asrc);
      *(h8*)(Adst + 8) = *(const h8*)(asrc + 8);
      h_t tmp[2][4];
#pragma unroll
      for (int kk = 0; kk < 2; ++kk) {
        const h_t* src = Ob + (long long)(c2 * 32 + kp * 2 + kk) * HW;
#pragma unroll
        for (int j = 0; j < 4; ++j) {
          int sy = py[j] + dy, sx = px[j] + dx;
          h_t v = (h_t)0.f;
          if (sy >= 0 && sy < H && sx >= 0 && sx < W) v = src[sy * W + sx];
          tmp[kk][j] = v;
        }
      }
#pragma unroll
      for (int j = 0; j < 4; ++j) {
        h2 v; v.x = tmp[0][j]; v.y = tmp[1][j];
        *(h2*)(Bdst + j * 40) = v;
      }
      __syncthreads();
      h8 bf[2];
#pragma unroll
      for (int nt = 0; nt < 2; ++nt)
        bf[nt] = *(const h8*)(Bs + (wn + nt * 16 + l15) * 40 + q * 8);
#pragma unroll
      for (int mt = 0; mt < 4; ++mt) {
        const int ro = (wm + mt * 16 + l15) * 40 + q * 8;
        h8 ahi = *(const h8*)(Ah + ro);
#pragma unroll
        for (int nt = 0; nt < 2; ++nt)
          acc[mt][nt] = __builtin_amdgcn_mfma_f32_16x16x32_f16(ahi, bf[nt], acc[mt][nt], 0, 0, 0);
      }
      __syncthreads();
    }
  }
  float* Cb = Cf + (long long)z * 216 * HW;
#pragma unroll
  for (int mt = 0; mt < 4; ++mt)
#pragma unroll
    for (int nt = 0; nt < 2; ++nt) {
      int n = p0 + wn + nt * 16 + l15;
#pragma unroll
      for (int r = 0; r < 4; ++r) {
        int row = mblk * 128 + wm + mt * 16 + q * 4 + r;
        if (row < 216)
          Cb[(long long)row * HW + n] = acc[mt][nt][r] + bias[row];
      }
    }
}

// ---------------- DCNv2 column build (fp16 out): col[bz][(g*32+c)*9+k][p] ----------------
__global__ void dcn_col_kernel(const float* __restrict__ x, const float* __restrict__ om,
                               h_t* __restrict__ col, int H, int W, int b0) {
  int HW = H * W;
  int p = blockIdx.x * 256 + threadIdx.x;
  int gk = blockIdx.y;           // 0..71
  int g = gk / 9, k9 = gk - g * 9;
  int bz = blockIdx.z;
  int b = b0 + bz;
  int h = p / W, wc = p - h * W;
  const float* omb = om + (long long)b * 216 * HW;
  float offy = omb[(long long)gk * HW + p];
  float offx = omb[(long long)(72 + gk) * HW + p];
  float mraw = omb[(long long)(144 + gk) * HW + p];
  float mask = 1.f / (1.f + expf(-mraw));
  float y = (float)h + (float)(k9 / 3 - 1) + offy;
  float xx = (float)wc + (float)(k9 % 3 - 1) + offx;
  float y0f = floorf(y), x0f = floorf(xx);
  int y0 = (int)y0f, x0 = (int)x0f;
  float fy = y - y0f, fx = xx - x0f;
  float w00 = (1.f - fy) * (1.f - fx), w01 = (1.f - fy) * fx;
  float w10 = fy * (1.f - fx), w11 = fy * fx;
  bool iy0 = (y0 >= 0) & (y0 < H), iy1 = (y0 + 1 >= 0) & (y0 + 1 < H);
  bool ix0 = (x0 >= 0) & (x0 < W), ix1 = (x0 + 1 >= 0) & (x0 + 1 < W);
  w00 = (iy0 & ix0) ? w00 : 0.f;
  w01 = (iy0 & ix1) ? w01 : 0.f;
  w10 = (iy1 & ix0) ? w10 : 0.f;
  w11 = (iy1 & ix1) ? w11 : 0.f;
  int y0c = min(max(y0, 0), H - 1), y1c = min(max(y0 + 1, 0), H - 1);
  int x0c = min(max(x0, 0), W - 1), x1c = min(max(x0 + 1, 0), W - 1);
  int i00 = y0c * W + x0c, i01 = y0c * W + x1c, i10 = y1c * W + x0c, i11 = y1c * W + x1c;
  const float* xb = x + ((long long)b * 256 + g * 32) * HW;
  h_t* cb = col + ((long long)bz * 2304 + (long long)(g * 32) * 9 + k9) * HW + p;
#pragma unroll 4
  for (int c = 0; c < 32; c++) {
    const float* xc = xb + (long long)c * HW;
    float v = w00 * xc[i00] + w01 * xc[i01] + w10 * xc[i10] + w11 * xc[i11];
    cb[(long long)c * 9 * HW] = (h_t)(v * mask);
  }
}

// ---------------- channel avg/max of up2x(f3c fp16) at 128x128 ----------------
// 4 threads per output pixel (quad-split channels), shuffle combine.
__global__ void avgmax_kernel(const h_t* __restrict__ f3c, float* __restrict__ am) {
  int tid = threadIdx.x;
  int P = blockIdx.x * 64 + (tid >> 2);   // global pixel 0..65535
  int cq = tid & 3;
  int b = P >> 14, p = P & 16383;
  int oh = p >> 7, ow = p & 127;
  int iy = oh >> 1, ix = ow >> 1;
  int iy2 = (oh & 1) ? min(iy + 1, 63) : max(iy - 1, 0);
  int ix2 = (ow & 1) ? min(ix + 1, 63) : max(ix - 1, 0);
  int i00 = iy * 64 + ix, i01 = iy * 64 + ix2, i10 = iy2 * 64 + ix, i11 = iy2 * 64 + ix2;
  const h_t* base = f3c + (long long)b * 512 * 4096 + (long long)cq * 4096;
  float sum = 0.f, mx = -3.4e38f;
  for (int c = 0; c < 128; c++) {
    const h_t* pc = base + (long long)c * 4 * 4096;
    float v = 0.5625f * (float)pc[i00] + 0.1875f * ((float)pc[i01] + (float)pc[i10])
            + 0.0625f * (float)pc[i11];
    sum += v;
    mx = fmaxf(mx, v);
  }
  sum += __shfl_xor(sum, 1); sum += __shfl_xor(sum, 2);
  mx = fmaxf(mx, __shfl_xor(mx, 1)); mx = fmaxf(mx, __shfl_xor(mx, 2));
  if (cq == 0) {
    am[(long long)b * 2 * 16384 + p] = sum * (1.f / 512.f);
    am[(long long)b * 2 * 16384 + 16384 + p] = mx;
  }
}

// ---------------- conv7x7 (2->1) + BN + sigmoid -> sa ----------------
__global__ void sa_kernel(const float* __restrict__ am, const float* __restrict__ w_sa,
                          const float* __restrict__ bn_g, const float* __restrict__ bn_b,
                          const float* __restrict__ bn_m, const float* __restrict__ bn_v,
                          float* __restrict__ sa) {
  int idx = blockIdx.x * 64 + threadIdx.x; // 4*16384, 64-thread blocks
  int b = idx >> 14, p = idx & 16383;
  int oh = p >> 7, ow = p & 127;
  float acc = 0.f;
  for (int ci = 0; ci < 2; ci++) {
    const float* base = am + ((long long)b * 2 + ci) * 16384;
    for (int dy = 0; dy < 7; dy++) {
      int yy = oh + dy - 3;
      if (yy < 0 || yy > 127) continue;
      for (int dx = 0; dx < 7; dx++) {
        int xx = ow + dx - 3;
        if (xx < 0 || xx > 127) continue;
        acc += w_sa[ci * 49 + dy * 7 + dx] * base[yy * 128 + xx];
      }
    }
  }
  float a = (acc - bn_m[0]) * rsqrtf(bn_v[0] + 1e-5f);
  a = a * bn_g[0] + bn_b[0];
  sa[idx] = 1.f / (1.f + expf(-a));
}

// ---------------- y = (1+sa)*up2x(z); emits per-block GN partial sums ----------------
// Each block covers 256 consecutive out elements (one (b,c), 2 rows).
__global__ __launch_bounds__(256) void final_y_kernel(
    const float* __restrict__ z, const float* __restrict__ sa,
    float* __restrict__ out, float2* __restrict__ partials) {
  long long idx = (long long)blockIdx.x * 256 + threadIdx.x; // 16,777,216
  int ow = (int)(idx & 127);
  long long t = idx >> 7;
  int oh = (int)(t & 127);
  t >>= 7;
  int c = (int)(t & 255);
  int b = (int)(t >> 8);
  int iy = oh >> 1, ix = ow >> 1;
  int iy2 = (oh & 1) ? min(iy + 1, 63) : max(iy - 1, 0);
  int ix2 = (ow & 1) ? min(ix + 1, 63) : max(ix - 1, 0);
  const float* zp = z + (long long)(b * 256 + c) * 4096;
  float v = 0.5625f * zp[iy * 64 + ix] + 0.1875f * (zp[iy * 64 + ix2] + zp[iy2 * 64 + ix])
          + 0.0625f * zp[iy2 * 64 + ix2];
  float s = sa[((long long)b << 14) + (oh << 7) + ow];
  float y = v * (1.f + s);
  out[idx] = y;
  // block partial sum/sumsq
  float ps = y, pss = y * y;
#pragma unroll
  for (int off = 32; off > 0; off >>= 1) {
    ps += __shfl_down(ps, off);
    pss += __shfl_down(pss, off);
  }
  __shared__ float rs[2][4];
  int lane = threadIdx.x & 63, wv = threadIdx.x >> 6;
  if (lane == 0) { rs[0][wv] = ps; rs[1][wv] = pss; }
  __syncthreads();
  if (threadIdx.x == 0) {
    float2 pr;
    pr.x = rs[0][0] + rs[0][1] + rs[0][2] + rs[0][3];
    pr.y = rs[1][0] + rs[1][1] + rs[1][2] + rs[1][3];
    partials[blockIdx.x] = pr;
  }
}

// ---------------- GN stage-2: reduce 512 partials per (b,g) -> mu, rstd ----------------
__global__ __launch_bounds__(256) void gn_reduce_kernel(const float2* __restrict__ partials,
                                                        float* __restrict__ stats) {
  int bg = blockIdx.x; // 0..127
  int b = bg >> 5, g = bg & 31;
  int base = b * 16384 + g * 512;
  float2 p0 = partials[base + threadIdx.x];
  float2 p1 = partials[base + 256 + threadIdx.x];
  float s = p0.x + p1.x, ss = p0.y + p1.y;
#pragma unroll
  for (int off = 32; off > 0; off >>= 1) {
    s += __shfl_down(s, off);
    ss += __shfl_down(ss, off);
  }
  __shared__ float rs[2][4];
  int lane = threadIdx.x & 63, wv = threadIdx.x >> 6;
  if (lane == 0) { rs[0][wv] = s; rs[1][wv] = ss; }
  __syncthreads();
  if (threadIdx.x == 0) {
    float S = rs[0][0] + rs[0][1] + rs[0][2] + rs[0][3];
    float SS = rs[1][0] + rs[1][1] + rs[1][2] + rs[1][3];
    float n = 8.f * 16384.f;
    float mu = S / n;
    float var = SS / n - mu * mu;
    stats[bg * 2] = mu;
    stats[bg * 2 + 1] = rsqrtf(var + 1e-5f);
  }
}

__global__ void gn_apply_kernel(float* __restrict__ y, const float* __restrict__ stats,
                                const float* __restrict__ gg, const float* __restrict__ gb) {
  long long i4 = (long long)blockIdx.x * 256 + threadIdx.x; // 4,194,304 float4s
  long long e = i4 << 2;
  int c = (int)((e >> 14) & 255);
  int b = (int)(e >> 22);
  int bg = b * 32 + (c >> 3);
  float mu = stats[bg * 2], rstd = stats[bg * 2 + 1];
  float sc = rstd * gg[c];
  float sh = gb[c] - mu * rstd * gg[c];
  f4 v = *(f4*)(y + e);
  v.x = v.x * sc + sh; v.y = v.y * sc + sh;
  v.z = v.z * sc + sh; v.w = v.w * sc + sh;
  *(f4*)(y + e) = v;
}

// ============================================================================

extern "C" void kernel_launch(void* const* d_in, const int* in_sizes, int n_in,
                              void* d_out, int out_size, void* d_ws, size_t ws_size,
                              hipStream_t stream) {
  const float* feat_3 = (const float*)d_in[1];
  const float* feat_4 = (const float*)d_in[2];
  const float* feat_5 = (const float*)d_in[3];
  const float* w_off5 = (const float*)d_in[4];
  const float* w_om5  = (const float*)d_in[5];
  const float* b_om5  = (const float*)d_in[6];
  const float* w_dcn5 = (const float*)d_in[7];
  const float* b_dcn5 = (const float*)d_in[8];
  const float* w_c1   = (const float*)d_in[9];
  const float* w_off4 = (const float*)d_in[10];
  const float* w_om4  = (const float*)d_in[11];
  const float* b_om4  = (const float*)d_in[12];
  const float* w_dcn4 = (const float*)d_in[13];
  const float* b_dcn4 = (const float*)d_in[14];
  const float* w_sa   = (const float*)d_in[15];
  const float* bn_g   = (const float*)d_in[16];
  const float* bn_b   = (const float*)d_in[17];
  const float* bn_m   = (const float*)d_in[18];
  const float* bn_v   = (const float*)d_in[19];
  const float* w_sem  = (const float*)d_in[20];
  const float* gn_g   = (const float*)d_in[21];
  const float* gn_b   = (const float*)d_in[22];
  float* out = (float*)d_out;
  float* ws = (float*)d_ws;

  // ---- workspace (float offsets) ----
  const long long o_Wp    = 0;                       // 2,883,584 f (fp16 weights)
  const long long o_up5   = o_Wp + 2883584;          // 1,048,576 (alias: am/sa/gnst/partials)
  const long long o_off5h = o_up5 + 1048576;         //   524,288 (fp16)
  const long long o_om5   = o_off5h + 524288;        //   884,736
  const long long o_a5    = o_om5 + 884736;          // 1,048,576
  const long long o_f4n   = o_a5 + 1048576;          // 1,048,576
  const long long o_up4   = o_f4n + 1048576;         // 4,194,304 (alias: z64)
  const long long o_off4h = o_up4 + 4194304;         // 2,097,152 (fp16; alias f4a fp16)
  const long long o_om4   = o_off4h + 2097152;       // 3,538,944
  const long long o_sh    = o_om4 + 3538944;         // shared: cat/col/f3c (fp16)

  const long long shAll = 18874368;                  // col4 all-batch (fp16, floats)
  bool allb = ws_size >= (size_t)(o_sh + shAll) * 4;

  h_t* WpH = (h_t*)ws;
  h_t* wp_off5 = WpH;
  h_t* wp_dcn5 = wp_off5 + 262144;
  h_t* wp_c1   = wp_dcn5 + 1179648;
  h_t* wp_om5  = wp_c1 + 262144;
  h_t* wp_off4 = wp_om5 + 1179648;
  h_t* wp_dcn4 = wp_off4 + 262144;
  h_t* wp_om4  = wp_dcn4 + 1179648;
  h_t* wp_sem  = wp_om4 + 1179648;

  float* up5   = ws + o_up5;
  h_t*   off5h = (h_t*)(ws + o_off5h);
  float* om5   = ws + o_om5;
  float* a5    = ws + o_a5;
  float* f4n   = ws + o_f4n;
  float* up4   = ws + o_up4;
  h_t*   off4h = (h_t*)(ws + o_off4h);
  float* om4   = ws + o_om4;
  h_t*   shH   = (h_t*)(ws + o_sh);
  h_t*   f4aH  = off4h;             // alias (off4 dead after mconv om4)
  float* z64   = up4;               // alias (up4 dead after col4 build)
  float* am    = up5;               // alias (up5 dead after col5 build)
  float* sa    = am + 131072;
  float* gnst  = sa + 65536;
  float2* gnpart = (float2*)(gnst + 256);  // 65536 float2 = 131072 floats

  dim3 blk(256);

  // ---- weight prep (fp16 hi/lo, swizzled; om convs tap-major) ----
  prep_w_kernel<0><<<cdiv(512LL * 512, 256), blk, 0, stream>>>(w_off5, wp_off5, 256, 512);
  prep_w_kernel<0><<<cdiv(512LL * 2304, 256), blk, 0, stream>>>(w_dcn5, wp_dcn5, 256, 2304);
  prep_w_kernel<0><<<cdiv(512LL * 512, 256), blk, 0, stream>>>(w_c1, wp_c1, 256, 512);
  prep_w_kernel<1><<<cdiv(512LL * 2304, 256), blk, 0, stream>>>(w_om5, wp_om5, 216, 2304);
  prep_w_kernel<0><<<cdiv(512LL * 512, 256), blk, 0, stream>>>(w_off4, wp_off4, 256, 512);
  prep_w_kernel<0><<<cdiv(512LL * 2304, 256), blk, 0, stream>>>(w_dcn4, wp_dcn4, 256, 2304);
  prep_w_kernel<1><<<cdiv(512LL * 2304, 256), blk, 0, stream>>>(w_om4, wp_om4, 216, 2304);
  prep_w_kernel<0><<<cdiv(512LL * 512, 256), blk, 0, stream>>>(w_sem, wp_sem, 256, 512);

  // ---- stage A (32x32, HW=1024) ----
  upsample2x_kernel<<<cdiv(1024LL * 1024, 256), blk, 0, stream>>>(feat_5, up5, 1024, 16, 16);
  concat_h_kernel<float><<<cdiv(4LL * 512 * 1024, 256), blk, 0, stream>>>(
      feat_4, up5, shH, 256, 256, 1024, 2.f);
  mgemm_kernel<0, 1, 0><<<dim3(16, 2, 4), blk, 0, stream>>>(
      wp_off5, shH, off5h, nullptr, 256, 1024, 512, 512LL * 1024, 256LL * 1024);
  mconv_kernel<5><<<dim3(16, 2, 4), blk, 0, stream>>>(wp_om5, off5h, om5, b_om5, 1024);
  dcn_col_kernel<<<dim3(4, 72, 4), blk, 0, stream>>>(up5, om5, shH, 32, 32, 0);
  mgemm_kernel<1, 0, 1><<<dim3(16, 2, 4), blk, 0, stream>>>(
      wp_dcn5, shH, a5, b_dcn5, 256, 1024, 2304, 2304LL * 1024, 256LL * 1024);
  concat_h_kernel<float><<<cdiv(4LL * 512 * 1024, 256), blk, 0, stream>>>(
      a5, feat_4, shH, 256, 256, 1024, 1.f);
  mgemm_kernel<0, 0, 1><<<dim3(16, 2, 4), blk, 0, stream>>>(
      wp_c1, shH, f4n, nullptr, 256, 1024, 512, 512LL * 1024, 256LL * 1024);

  // ---- stage B (64x64, HW=4096) ----
  upsample2x_kernel<<<cdiv(4194304LL, 256), blk, 0, stream>>>(f4n, up4, 1024, 32, 32);
  concat_h_kernel<float><<<cdiv(4LL * 512 * 4096, 256), blk, 0, stream>>>(
      feat_3, up4, shH, 256, 256, 4096, 2.f);
  mgemm_kernel<0, 1, 0><<<dim3(64, 2, 4), blk, 0, stream>>>(
      wp_off4, shH, off4h, nullptr, 256, 4096, 512, 512LL * 4096, 256LL * 4096);
  mconv_kernel<6><<<dim3(64, 2, 4), blk, 0, stream>>>(wp_om4, off4h, om4, b_om4, 4096);
  if (allb) {
    dcn_col_kernel<<<dim3(16, 72, 4), blk, 0, stream>>>(up4, om4, shH, 64, 64, 0);
    mgemm_kernel<1, 1, 1><<<dim3(64, 2, 4), blk, 0, stream>>>(
        wp_dcn4, shH, f4aH, b_dcn4, 256, 4096, 2304, 2304LL * 4096, 256LL * 4096);
  } else {
    for (int b = 0; b < 4; b++) {
      dcn_col_kernel<<<dim3(16, 72, 1), blk, 0, stream>>>(up4, om4, shH, 64, 64, b);
      mgemm_kernel<1, 1, 1><<<dim3(64, 2, 1), blk, 0, stream>>>(
          wp_dcn4, shH, f4aH + (long long)b * 1048576, b_dcn4, 256, 4096, 2304, 0, 0);
    }
  }
  concat_h_kernel<h_t><<<cdiv(4LL * 512 * 4096, 256), blk, 0, stream>>>(
      f4aH, feat_3, shH, 256, 256, 4096, 1.f);

  // ---- SEM head ----
  avgmax_kernel<<<1024, blk, 0, stream>>>(shH, am);
  sa_kernel<<<1024, dim3(64), 0, stream>>>(am, w_sa, bn_g, bn_b, bn_m, bn_v, sa);
  mgemm_kernel<0, 0, 1><<<dim3(64, 2, 4), blk, 0, stream>>>(
      wp_sem, shH, z64, nullptr, 256, 4096, 512, 512LL * 4096, 256LL * 4096);
  final_y_kernel<<<65536, blk, 0, stream>>>(z64, sa, out, gnpart);
  gn_reduce_kernel<<<128, blk, 0, stream>>>(gnpart, gnst);
  gn_apply_kernel<<<16384, blk, 0, stream>>>(out, gnst, gn_g, gn_b);
}